// Round 10
// baseline (391.228 us; speedup 1.0000x reference)
//
#include <hip/hip_runtime.h>

// ---------------- problem constants ----------------
#define Bb 8
#define Tt 1024
#define Hh 8
#define DKk 64
#define NFf 512
#define DCc 256

typedef _Float16 v2h __attribute__((ext_vector_type(2)));
typedef _Float16 v4h __attribute__((ext_vector_type(4)));
typedef _Float16 v8h __attribute__((ext_vector_type(8)));
typedef float    v4f __attribute__((ext_vector_type(4)));
typedef float    v16f __attribute__((ext_vector_type(16)));

#define MFMA32(a,b,c) __builtin_amdgcn_mfma_f32_16x16x32_f16((a),(b),(c),0,0,0)
#define MFMA3216(a,b,c) __builtin_amdgcn_mfma_f32_32x32x16_f16((a),(b),(c),0,0,0)

// scale folded into q: 1/sqrt(64) * log2(e)  (scores live in log2 domain)
#define SCQ 0.1803368801111f

__device__ inline void st8(_Float16* dst, v8h x){
    *(v4h*)dst     = __builtin_shufflevector(x,x,0,1,2,3);
    *(v4h*)(dst+4) = __builtin_shufflevector(x,x,4,5,6,7);
}

__device__ inline v8h cvt8(float4 a, float4 b){
    v8h r;
    r[0]=(_Float16)a.x; r[1]=(_Float16)a.y; r[2]=(_Float16)a.z; r[3]=(_Float16)a.w;
    r[4]=(_Float16)b.x; r[5]=(_Float16)b.y; r[6]=(_Float16)b.z; r[7]=(_Float16)b.w;
    return r;
}

__device__ inline v8h cvt8v(v4f a, v4f b){
    v8h r;
    r[0]=(_Float16)a[0]; r[1]=(_Float16)a[1]; r[2]=(_Float16)a[2]; r[3]=(_Float16)a[3];
    r[4]=(_Float16)b[0]; r[5]=(_Float16)b[1]; r[6]=(_Float16)b[2]; r[7]=(_Float16)b[3];
    return r;
}

__device__ inline v4f ntl4(const float* p){
    return __builtin_nontemporal_load(reinterpret_cast<const v4f*>(p));
}

// XOR swizzle for [R][64] half LDS tiles; keeps 8-half granularity
__device__ inline int swz(int r, int c){ return (r*64 + c) ^ ((r&7)<<3); }

// ---------------- LayerNorm: x (8192,512) fp32 -> xn fp16 ----------------
__global__ __launch_bounds__(256) void k_ln(const float* __restrict__ x,
                                            const float* __restrict__ g,
                                            const float* __restrict__ be,
                                            _Float16* __restrict__ xn){
    int row = blockIdx.x; int tid = threadIdx.x;
    const float* xr = x + (size_t)row*512;
    float2 v = reinterpret_cast<const float2*>(xr)[tid];
    float s = v.x + v.y, sq = v.x*v.x + v.y*v.y;
    for (int off=32; off; off>>=1){ s += __shfl_down(s, off); sq += __shfl_down(sq, off); }
    __shared__ float ws_[4], wq_[4];
    __shared__ float mu_s, rs_s;
    int wid = tid>>6, lid = tid&63;
    if (lid==0){ ws_[wid]=s; wq_[wid]=sq; }
    __syncthreads();
    if (tid==0){
        float S=0,Q=0;
        for(int i=0;i<4;i++){S+=ws_[i];Q+=wq_[i];}
        float mu = S*(1.f/512.f);
        float var = Q*(1.f/512.f)-mu*mu;
        mu_s=mu; rs_s=rsqrtf(var+1e-5f);
    }
    __syncthreads();
    float mu=mu_s, rs=rs_s;
    float2 gv = reinterpret_cast<const float2*>(g)[tid];
    float2 bv = reinterpret_cast<const float2*>(be)[tid];
    v2h o; o[0] = (_Float16)((v.x-mu)*rs*gv.x + bv.x);
           o[1] = (_Float16)((v.y-mu)*rs*gv.y + bv.y);
    reinterpret_cast<v2h*>(xn + (size_t)row*512)[tid] = o;
}

// ---------------- weight transpose: W (512,512) fp32 -> WT (N,K) fp16 --------
__global__ __launch_bounds__(256) void k_wT(const float* __restrict__ W,
                                            _Float16* __restrict__ WT){
    __shared__ float tile[64][65];
    int bx = blockIdx.x*64, by = blockIdx.y*64;   // bx: n-base, by: k-base
    int tid = threadIdx.x, c = tid&63;
    for (int r = tid>>6; r<64; r+=4) tile[r][c] = W[(size_t)(by+r)*512 + bx + c];
    __syncthreads();
    for (int n = tid>>6; n<64; n+=4) WT[(size_t)(bx+n)*512 + by + c] = (_Float16)tile[c][n];
}

// ---------------- wcqT = (Wc @ Wq)^T fp16 [512][256] ----------------
__global__ __launch_bounds__(512) void k_wcq(const float* __restrict__ Wc,
                                             const float* __restrict__ Wq,
                                             _Float16* __restrict__ wcqT){
    __shared__ float wc[8][512];
    int i0 = blockIdx.x*8; int tid = threadIdx.x;
    for (int r=0;r<8;r++) wc[r][tid] = Wc[(size_t)(i0+r)*512 + tid];
    __syncthreads();
    float acc[8] = {0,0,0,0,0,0,0,0};
    for (int m=0;m<512;m++){
        float wq = Wq[(size_t)m*512+tid];
        #pragma unroll
        for (int r=0;r<8;r++) acc[r] += wc[r][m]*wq;
    }
    for (int r=0;r<8;r++) wcqT[(size_t)tid*256 + i0 + r] = (_Float16)acc[r];
}

// ---------------- bcq = bc @ Wq + bq ----------------
__global__ __launch_bounds__(512) void k_bcq(const float* __restrict__ bc,
                                             const float* __restrict__ Wq,
                                             const float* __restrict__ bq,
                                             float* __restrict__ bcq){
    int j = threadIdx.x;
    float a = bq[j];
    for (int m=0;m<512;m++) a += bc[m]*Wq[(size_t)m*512+j];
    bcq[j] = a;
}

// ---------------- GEMM v2: C(M,N) = (A(M,K) @ WT(N,K)^T + bias)*scale --------
template<typename AT, typename CT, bool QB>
__global__ __launch_bounds__(256) void k_gemm(const AT* __restrict__ A,
                                              const _Float16* __restrict__ WT,
                                              const float* __restrict__ bias,
                                              CT* __restrict__ C,
                                              int M, int N, int K,
                                              float scale,
                                              _Float16* __restrict__ qbT){
    __shared__ _Float16 Al[64*64];
    __shared__ _Float16 Wl[64*64];
    int tid = threadIdx.x; int l = tid & 63; int w = tid >> 6;
    int l15 = l & 15, lq = l >> 4;
    int m0 = blockIdx.y*64, n0 = blockIdx.x*64;
    v4f acc[4] = {};
    float bv[4];
    #pragma unroll
    for (int nt=0;nt<4;nt++) bv[nt] = bias[n0 + nt*16 + l15];
    int srow = tid>>2, sseg = (tid&3)*16;
    for (int k0=0;k0<K;k0+=64){
        if constexpr (sizeof(AT)==4){
            const float* src = (const float*)A + (size_t)(m0+srow)*K + k0 + sseg;
            float4 f0 = *(const float4*)src;
            float4 f1 = *(const float4*)(src+4);
            float4 f2 = *(const float4*)(src+8);
            float4 f3 = *(const float4*)(src+12);
            st8(&Al[swz(srow, sseg)],   cvt8(f0,f1));
            st8(&Al[swz(srow, sseg+8)], cvt8(f2,f3));
        } else {
            const _Float16* src = (const _Float16*)A + (size_t)(m0+srow)*K + k0 + sseg;
            v8h h0 = *(const v8h*)src;
            v8h h1 = *(const v8h*)(src+8);
            st8(&Al[swz(srow, sseg)],   h0);
            st8(&Al[swz(srow, sseg+8)], h1);
        }
        {
            const _Float16* src = WT + (size_t)(n0+srow)*K + k0 + sseg;
            v8h h0 = *(const v8h*)src;
            v8h h1 = *(const v8h*)(src+8);
            st8(&Wl[swz(srow, sseg)],   h0);
            st8(&Wl[swz(srow, sseg+8)], h1);
        }
        __syncthreads();
        #pragma unroll
        for (int kk=0; kk<2; ++kk){
            v8h a = *(const v8h*)&Al[swz(w*16 + l15, kk*32 + lq*8)];
            #pragma unroll
            for (int nt=0;nt<4;nt++){
                v8h b = *(const v8h*)&Wl[swz(nt*16 + l15, kk*32 + lq*8)];
                acc[nt] = MFMA32(a, b, acc[nt]);
            }
        }
        __syncthreads();
    }
    #pragma unroll
    for (int nt=0;nt<4;nt++){
        #pragma unroll
        for (int i=0;i<4;i++){
            int row = m0 + w*16 + lq*4 + i;
            int col = n0 + nt*16 + l15;
            float vfull = (acc[nt][i] + bv[nt])*scale;
            C[(size_t)row*N + col] = (CT)vfull;
            if constexpr (QB){
                int bI = row>>10, t = row&1023;
                qbT[((size_t)t<<12) + (bI<<9) + col] = (_Float16)vfull;
            }
        }
    }
}

// ---------------- fused K+V projection: one A-stage, two MFMA streams --------
__global__ __launch_bounds__(256) void k_gemmkv(const _Float16* __restrict__ A,
                                                const _Float16* __restrict__ WTk,
                                                const _Float16* __restrict__ WTv,
                                                const float* __restrict__ bk,
                                                const float* __restrict__ bv,
                                                _Float16* __restrict__ Ck,
                                                _Float16* __restrict__ Cv){
    __shared__ _Float16 Al[64*64];
    __shared__ _Float16 Wkl[64*64];
    __shared__ _Float16 Wvl[64*64];
    int tid = threadIdx.x; int l = tid & 63; int w = tid >> 6;
    int l15 = l & 15, lq = l >> 4;
    int m0 = blockIdx.y*64, n0 = blockIdx.x*64;
    v4f ak[4] = {}, av[4] = {};
    float bkr[4], bvr[4];
    #pragma unroll
    for (int nt=0;nt<4;nt++){ bkr[nt] = bk[n0 + nt*16 + l15]; bvr[nt] = bv[n0 + nt*16 + l15]; }
    int srow = tid>>2, sseg = (tid&3)*16;
    for (int k0=0;k0<512;k0+=64){
        {
            const _Float16* src = A + (size_t)(m0+srow)*512 + k0 + sseg;
            v8h h0 = *(const v8h*)src;
            v8h h1 = *(const v8h*)(src+8);
            st8(&Al[swz(srow, sseg)],   h0);
            st8(&Al[swz(srow, sseg+8)], h1);
        }
        {
            const _Float16* src = WTk + (size_t)(n0+srow)*512 + k0 + sseg;
            v8h h0 = *(const v8h*)src;
            v8h h1 = *(const v8h*)(src+8);
            st8(&Wkl[swz(srow, sseg)],   h0);
            st8(&Wkl[swz(srow, sseg+8)], h1);
        }
        {
            const _Float16* src = WTv + (size_t)(n0+srow)*512 + k0 + sseg;
            v8h h0 = *(const v8h*)src;
            v8h h1 = *(const v8h*)(src+8);
            st8(&Wvl[swz(srow, sseg)],   h0);
            st8(&Wvl[swz(srow, sseg+8)], h1);
        }
        __syncthreads();
        #pragma unroll
        for (int kk=0; kk<2; ++kk){
            v8h a = *(const v8h*)&Al[swz(w*16 + l15, kk*32 + lq*8)];
            #pragma unroll
            for (int nt=0;nt<4;nt++){
                v8h wk = *(const v8h*)&Wkl[swz(nt*16 + l15, kk*32 + lq*8)];
                v8h wv = *(const v8h*)&Wvl[swz(nt*16 + l15, kk*32 + lq*8)];
                ak[nt] = MFMA32(a, wk, ak[nt]);
                av[nt] = MFMA32(a, wv, av[nt]);
            }
        }
        __syncthreads();
    }
    #pragma unroll
    for (int nt=0;nt<4;nt++){
        #pragma unroll
        for (int i=0;i<4;i++){
            int row = m0 + w*16 + lq*4 + i;
            int col = n0 + nt*16 + l15;
            Ck[(size_t)row*512 + col] = (_Float16)(ak[nt][i] + bkr[nt]);
            Cv[(size_t)row*512 + col] = (_Float16)(av[nt][i] + bvr[nt]);
        }
    }
}

// ---------------- bias v5: Sb[t][bh][s] = qb[t,bh,:]·posk[t,s,:], mask folded
// grid 2048 (t = blk>>1, s-half = blk&1), 256 thr; wave owns 128 s = 4 groups.
// Rolling depth-2 register pipeline over groups; pos_k NT; Sb stores NORMAL
// (L3-resident for k_flash).
__global__ __launch_bounds__(256) void k_bias(const _Float16* __restrict__ qb,
                                              const float* __restrict__ posk,
                                              const int* __restrict__ mask,
                                              _Float16* __restrict__ Sb){
    int t = blockIdx.x >> 1, sh = blockIdx.x & 1;
    int tid = threadIdx.x, l = tid&63, w = tid>>6;
    int l31 = l&31, hi = l>>5;
    v8h aa[2][4];
    const _Float16* qbt = qb + ((size_t)t<<12);
    #pragma unroll
    for (int g=0; g<2; ++g)
        #pragma unroll
        for (int k0=0;k0<4;++k0)
            aa[g][k0] = *(const v8h*)(qbt + (g*32 + l31)*64 + k0*16 + hi*8);
    const float* pkt = posk + ((size_t)t<<16);
    int sbase = sh*512 + w*128;
    // all mask values up front (oldest loads, retired first)
    int mv[4][8];
    #pragma unroll
    for (int gr=0; gr<4; ++gr)
        #pragma unroll
        for (int q=0;q<8;++q)
            mv[gr][q] = mask[(((size_t)(q*Tt + t))<<10) + sbase + gr*32 + l31];

#define LOADG(P, gr) { const float* prow_ = pkt + (size_t)(sbase + (gr)*32 + l31)*64 + hi*8; \
    _Pragma("unroll") for (int k_=0;k_<4;++k_){ P[2*k_] = ntl4(prow_ + k_*16); P[2*k_+1] = ntl4(prow_ + k_*16 + 4); } }

#define COMPUTE(P, gr) { v8h bf_[4]; \
    _Pragma("unroll") for (int k_=0;k_<4;++k_) bf_[k_] = cvt8v(P[2*k_], P[2*k_+1]); \
    int sA_ = sbase + (gr)*32; \
    _Pragma("unroll") for (int g_=0; g_<2; ++g_){ \
        v16f acc_ = {}; \
        _Pragma("unroll") for (int k_=0;k_<4;++k_) acc_ = MFMA3216(aa[g_][k_], bf_[k_], acc_); \
        _Pragma("unroll") for (int r_=0;r_<16;++r_){ \
            int bh_ = g_*32 + (r_&3) + 4*hi + 8*(r_>>2); \
            _Float16 val_ = mv[gr][g_*4 + (r_>>2)] ? (_Float16)acc_[r_] : (_Float16)(-30000.f); \
            Sb[(((size_t)(t*64 + bh_))<<10) + sA_ + l31] = val_; } } }

    v4f pA[8], pB[8];
    LOADG(pA, 0); LOADG(pB, 1);
    COMPUTE(pA, 0); LOADG(pA, 2);
    COMPUTE(pB, 1); LOADG(pB, 3);
    COMPUTE(pA, 2);
    COMPUTE(pB, 3);
#undef LOADG
#undef COMPUTE
}

// ---------------- flash: content QK + bias + online softmax + PV -------------
// grid (64 bh, 8 t-tiles of 128), 512 thr. T14 async-stage: chunk sc+1's
// global loads issue right after the first barrier, landing during compute.
// Sb reads NORMAL (L3-resident after k_bias).
__global__ __launch_bounds__(512) void k_flash(const _Float16* __restrict__ qs,
                                               const _Float16* __restrict__ kbuf,
                                               const _Float16* __restrict__ vbuf,
                                               const _Float16* __restrict__ Sb,
                                               _Float16* __restrict__ ao){
    __shared__ _Float16 Kl[64*64];    // [s][d] swizzled
    __shared__ _Float16 Vt[64*64];    // [d][s] swizzled
    __shared__ _Float16 Bl[128*64];   // bias chunk then P, [t][s] swizzled
    int bh = blockIdx.x; int b = bh>>3, h = bh&7;
    int t0 = blockIdx.y*128;
    int tid = threadIdx.x, l = tid&63, w = tid>>6, l15 = l&15, lq = l>>4;

    // resident Q A-frags (scaled fp16), rows t0 + w*16 + l15
    v8h qa[2];
    #pragma unroll
    for (int u=0;u<2;++u)
        qa[u] = *(const v8h*)(qs + ((size_t)(b*Tt + t0 + w*16 + l15))*NFf + h*DKk + u*32 + lq*8);

    v4f O[4] = {};
    float mrow[4], lrow[4];
    #pragma unroll
    for (int i=0;i<4;i++){ mrow[i] = -1e30f; lrow[i] = 0.f; }

    // staging geometry
    int kr = tid>>3, kseg = (tid&7)*8;
    int vs = tid&63, vd0 = (tid>>6)*8;
    int br = tid>>2, bhf = (tid&3)*16;
    const _Float16* kbase = kbuf + ((size_t)(b*Tt + kr))*NFf + h*DKk + kseg;
    const _Float16* vbase = vbuf + ((size_t)(b*Tt + vs))*NFf + h*DKk + vd0;
    const _Float16* bbase = Sb + (((size_t)((t0+br)*64 + bh))<<10) + bhf;

    // prefetch chunk 0
    v8h pk = *(const v8h*)kbase;
    v8h pv = *(const v8h*)vbase;
    v8h pb0 = *(const v8h*)bbase;
    v8h pb1 = *((const v8h*)bbase + 1);

    for (int sc=0; sc<16; ++sc){
        // write staged regs to LDS
        st8(&Kl[swz(kr, kseg)], pk);
        #pragma unroll
        for (int j=0;j<8;j++) Vt[swz(vd0+j, vs)] = pv[j];
        st8(&Bl[swz(br, bhf)],   pb0);
        st8(&Bl[swz(br, bhf+8)], pb1);
        __syncthreads();
        // issue next chunk's loads (land during compute below)
        if (sc < 15){
            size_t soff = (size_t)(sc+1)*64;
            pk  = *(const v8h*)(kbase + soff*NFf);
            pv  = *(const v8h*)(vbase + soff*NFf);
            pb0 = *(const v8h*)(bbase + soff);
            pb1 = *((const v8h*)(bbase + soff) + 1);
        }

        v4f sv[4];
        #pragma unroll
        for (int nt=0; nt<4; ++nt){
            v8h kb0 = *(v8h*)&Kl[swz(nt*16+l15, lq*8)];
            v8h kb1 = *(v8h*)&Kl[swz(nt*16+l15, 32+lq*8)];
            v4f a = {};
            a = MFMA32(qa[0], kb0, a);
            a = MFMA32(qa[1], kb1, a);
            int rb = w*16;
            #pragma unroll
            for (int i=0;i<4;i++)
                a[i] += (float)Bl[swz(rb + lq*4 + i, nt*16 + l15)];
            sv[nt] = a;
        }
        // online softmax with defer-max (exact: skipping when no growth is bit-exact)
        float mn[4]; float grow = 0.f;
        #pragma unroll
        for (int i=0;i<4;i++){
            float mx = fmaxf(fmaxf(sv[0][i],sv[1][i]),fmaxf(sv[2][i],sv[3][i]));
            mx = fmaxf(mx, __shfl_xor(mx,1));
            mx = fmaxf(mx, __shfl_xor(mx,2));
            mx = fmaxf(mx, __shfl_xor(mx,4));
            mx = fmaxf(mx, __shfl_xor(mx,8));
            mn[i] = fmaxf(mrow[i], mx);
            grow = fmaxf(grow, mn[i] - mrow[i]);
        }
        if (__any(grow > 0.f)){
            #pragma unroll
            for (int i=0;i<4;i++){
                float rsc = exp2f(mrow[i] - mn[i]);
                mrow[i] = mn[i];
                lrow[i] *= rsc;
                #pragma unroll
                for (int nt=0; nt<4; ++nt) O[nt][i] *= rsc;
            }
        }
        #pragma unroll
        for (int i=0;i<4;i++){
            float ps = 0.f;
            #pragma unroll
            for (int nt=0; nt<4; ++nt){
                float pv2 = exp2f(sv[nt][i] - mrow[i]);
                sv[nt][i] = pv2;
                ps += pv2;
            }
            ps += __shfl_xor(ps,1);
            ps += __shfl_xor(ps,2);
            ps += __shfl_xor(ps,4);
            ps += __shfl_xor(ps,8);
            lrow[i] += ps;
        }
        // write P (fp16) into Bl over this wave's rows
        #pragma unroll
        for (int nt=0;nt<4;++nt){
            #pragma unroll
            for (int i=0;i<4;i++)
                Bl[swz(w*16+lq*4+i, nt*16+l15)] = (_Float16)sv[nt][i];
        }
        // PV: A = P rows (own wave), B = Vt
        {
            v8h pa0 = *(v8h*)&Bl[swz(w*16+l15, lq*8)];
            v8h pa1 = *(v8h*)&Bl[swz(w*16+l15, 32+lq*8)];
            #pragma unroll
            for (int nt=0; nt<4; ++nt){
                v8h vb0 = *(v8h*)&Vt[swz(nt*16+l15, lq*8)];
                v8h vb1 = *(v8h*)&Vt[swz(nt*16+l15, 32+lq*8)];
                O[nt] = MFMA32(pa0, vb0, O[nt]);
                O[nt] = MFMA32(pa1, vb1, O[nt]);
            }
        }
        __syncthreads();
    }

    #pragma unroll
    for (int i=0;i<4;i++){
        float lr = lrow[i];
        float rl = (lr > 0.f) ? 1.f/lr : 0.f;
        int row = t0 + w*16 + lq*4 + i;
        #pragma unroll
        for (int nt=0; nt<4; ++nt)
            ao[((size_t)(b*Tt + row))*NFf + h*DKk + nt*16 + l15] = (_Float16)(O[nt][i]*rl);
    }
}

// ---------------- launch ----------------
extern "C" void kernel_launch(void* const* d_in, const int* in_sizes, int n_in,
                              void* d_out, int out_size, void* d_ws, size_t ws_size,
                              hipStream_t stream) {
    const float* x       = (const float*)d_in[0];
    const float* cond    = (const float*)d_in[1];
    const float* pos_k   = (const float*)d_in[2];
    const int*   mask    = (const int*)  d_in[3];
    const float* ln_g    = (const float*)d_in[4];
    const float* ln_b    = (const float*)d_in[5];
    const float* Wq      = (const float*)d_in[6];
    const float* bq      = (const float*)d_in[7];
    const float* Wk      = (const float*)d_in[8];
    const float* bk      = (const float*)d_in[9];
    const float* Wv      = (const float*)d_in[10];
    const float* bv      = (const float*)d_in[11];
    const float* Wo      = (const float*)d_in[12];
    const float* bo      = (const float*)d_in[13];
    const float* Wc      = (const float*)d_in[14];
    const float* bc      = (const float*)d_in[15];
    float* out = (float*)d_out;

    char* base = (char*)d_ws;
    const size_t OFF_S    = 0;                       // 134217728 B fp16 Sb
    const size_t OFF_XN   = 134217728;
    const size_t OFF_Q    = OFF_XN  + 8388608;
    const size_t OFF_QB   = OFF_Q   + 8388608;
    const size_t OFF_K    = OFF_QB  + 8388608;
    const size_t OFF_V    = OFF_K   + 8388608;
    const size_t OFF_AO   = OFF_V   + 8388608;
    const size_t OFF_WKT  = OFF_AO  + 8388608;       // 524288
    const size_t OFF_WVT  = OFF_WKT + 524288;
    const size_t OFF_WOT  = OFF_WVT + 524288;
    const size_t OFF_WCQT = OFF_WOT + 524288;        // 262144
    const size_t OFF_BCQ  = OFF_WCQT + 262144;

    _Float16* xn    = (_Float16*)(base + OFF_XN);
    _Float16* qbuf  = (_Float16*)(base + OFF_Q);
    _Float16* qb    = (_Float16*)(base + OFF_QB);
    _Float16* kb    = (_Float16*)(base + OFF_K);
    _Float16* vb    = (_Float16*)(base + OFF_V);
    _Float16* ao    = (_Float16*)(base + OFF_AO);
    _Float16* Sb    = (_Float16*)(base + OFF_S);
    _Float16* WkT   = (_Float16*)(base + OFF_WKT);
    _Float16* WvT   = (_Float16*)(base + OFF_WVT);
    _Float16* WoT   = (_Float16*)(base + OFF_WOT);
    _Float16* wcqT  = (_Float16*)(base + OFF_WCQT);
    float*    bcq   = (float*)(base + OFF_BCQ);

    k_ln<<<dim3(Bb*Tt), dim3(256), 0, stream>>>(x, ln_g, ln_b, xn);
    k_wT<<<dim3(8,8), dim3(256), 0, stream>>>(Wk, WkT);
    k_wT<<<dim3(8,8), dim3(256), 0, stream>>>(Wv, WvT);
    k_wT<<<dim3(8,8), dim3(256), 0, stream>>>(Wo, WoT);
    k_wcq<<<dim3(32), dim3(512), 0, stream>>>(Wc, Wq, wcqT);
    k_bcq<<<dim3(1), dim3(512), 0, stream>>>(bc, Wq, bq, bcq);

    // q projection: writes scaled qbuf AND scaled transposed qb
    k_gemm<float,_Float16,true><<<dim3(8,128), dim3(256), 0, stream>>>(cond, wcqT, bcq, qbuf, Bb*Tt, 512, 256, SCQ, qb);
    // fused K+V projection
    k_gemmkv<<<dim3(8,128), dim3(256), 0, stream>>>(xn, WkT, WvT, bk, bv, kb, vb);

    k_bias<<<dim3(2048), dim3(256), 0, stream>>>(qb, pos_k, mask, Sb);
    k_flash<<<dim3(64,8), dim3(512), 0, stream>>>(qbuf, kb, vb, Sb, ao);

    k_gemm<_Float16,float,false><<<dim3(8,128), dim3(256), 0, stream>>>(ao, WoT, bo, out, Bb*Tt, 512, 512, 1.f, nullptr);
}

// Round 11
// 355.132 us; speedup vs baseline: 1.1016x; 1.1016x over previous
//
#include <hip/hip_runtime.h>

// ---------------- problem constants ----------------
#define Bb 8
#define Tt 1024
#define Hh 8
#define DKk 64
#define NFf 512
#define DCc 256

typedef _Float16 v2h __attribute__((ext_vector_type(2)));
typedef _Float16 v4h __attribute__((ext_vector_type(4)));
typedef _Float16 v8h __attribute__((ext_vector_type(8)));
typedef float    v4f __attribute__((ext_vector_type(4)));
typedef float    v16f __attribute__((ext_vector_type(16)));

#define MFMA32(a,b,c) __builtin_amdgcn_mfma_f32_16x16x32_f16((a),(b),(c),0,0,0)
#define MFMA3216(a,b,c) __builtin_amdgcn_mfma_f32_32x32x16_f16((a),(b),(c),0,0,0)

// scale folded into q: 1/sqrt(64) * log2(e)  (scores live in log2 domain)
#define SCQ 0.1803368801111f

__device__ inline void st8(_Float16* dst, v8h x){
    *(v4h*)dst     = __builtin_shufflevector(x,x,0,1,2,3);
    *(v4h*)(dst+4) = __builtin_shufflevector(x,x,4,5,6,7);
}

__device__ inline v8h cvt8(float4 a, float4 b){
    v8h r;
    r[0]=(_Float16)a.x; r[1]=(_Float16)a.y; r[2]=(_Float16)a.z; r[3]=(_Float16)a.w;
    r[4]=(_Float16)b.x; r[5]=(_Float16)b.y; r[6]=(_Float16)b.z; r[7]=(_Float16)b.w;
    return r;
}

// XOR swizzle for [R][64] half LDS tiles; keeps 8-half granularity
__device__ inline int swz(int r, int c){ return (r*64 + c) ^ ((r&7)<<3); }

// ---------------- LayerNorm: x (8192,512) fp32 -> xn fp16 ----------------
__global__ __launch_bounds__(256) void k_ln(const float* __restrict__ x,
                                            const float* __restrict__ g,
                                            const float* __restrict__ be,
                                            _Float16* __restrict__ xn){
    int row = blockIdx.x; int tid = threadIdx.x;
    const float* xr = x + (size_t)row*512;
    float2 v = reinterpret_cast<const float2*>(xr)[tid];
    float s = v.x + v.y, sq = v.x*v.x + v.y*v.y;
    for (int off=32; off; off>>=1){ s += __shfl_down(s, off); sq += __shfl_down(sq, off); }
    __shared__ float ws_[4], wq_[4];
    __shared__ float mu_s, rs_s;
    int wid = tid>>6, lid = tid&63;
    if (lid==0){ ws_[wid]=s; wq_[wid]=sq; }
    __syncthreads();
    if (tid==0){
        float S=0,Q=0;
        for(int i=0;i<4;i++){S+=ws_[i];Q+=wq_[i];}
        float mu = S*(1.f/512.f);
        float var = Q*(1.f/512.f)-mu*mu;
        mu_s=mu; rs_s=rsqrtf(var+1e-5f);
    }
    __syncthreads();
    float mu=mu_s, rs=rs_s;
    float2 gv = reinterpret_cast<const float2*>(g)[tid];
    float2 bv = reinterpret_cast<const float2*>(be)[tid];
    v2h o; o[0] = (_Float16)((v.x-mu)*rs*gv.x + bv.x);
           o[1] = (_Float16)((v.y-mu)*rs*gv.y + bv.y);
    reinterpret_cast<v2h*>(xn + (size_t)row*512)[tid] = o;
}

// ---------------- weight transpose: W (512,512) fp32 -> WT (N,K) fp16 --------
__global__ __launch_bounds__(256) void k_wT(const float* __restrict__ W,
                                            _Float16* __restrict__ WT){
    __shared__ float tile[64][65];
    int bx = blockIdx.x*64, by = blockIdx.y*64;   // bx: n-base, by: k-base
    int tid = threadIdx.x, c = tid&63;
    for (int r = tid>>6; r<64; r+=4) tile[r][c] = W[(size_t)(by+r)*512 + bx + c];
    __syncthreads();
    for (int n = tid>>6; n<64; n+=4) WT[(size_t)(bx+n)*512 + by + c] = (_Float16)tile[c][n];
}

// ---------------- wcqT = (Wc @ Wq)^T fp16 [512][256] ----------------
__global__ __launch_bounds__(512) void k_wcq(const float* __restrict__ Wc,
                                             const float* __restrict__ Wq,
                                             _Float16* __restrict__ wcqT){
    __shared__ float wc[8][512];
    int i0 = blockIdx.x*8; int tid = threadIdx.x;
    for (int r=0;r<8;r++) wc[r][tid] = Wc[(size_t)(i0+r)*512 + tid];
    __syncthreads();
    float acc[8] = {0,0,0,0,0,0,0,0};
    for (int m=0;m<512;m++){
        float wq = Wq[(size_t)m*512+tid];
        #pragma unroll
        for (int r=0;r<8;r++) acc[r] += wc[r][m]*wq;
    }
    for (int r=0;r<8;r++) wcqT[(size_t)tid*256 + i0 + r] = (_Float16)acc[r];
}

// ---------------- bcq = bc @ Wq + bq ----------------
__global__ __launch_bounds__(512) void k_bcq(const float* __restrict__ bc,
                                             const float* __restrict__ Wq,
                                             const float* __restrict__ bq,
                                             float* __restrict__ bcq){
    int j = threadIdx.x;
    float a = bq[j];
    for (int m=0;m<512;m++) a += bc[m]*Wq[(size_t)m*512+j];
    bcq[j] = a;
}

// ---------------- GEMM v2: C(M,N) = (A(M,K) @ WT(N,K)^T + bias)*scale --------
template<typename AT, typename CT, bool QB>
__global__ __launch_bounds__(256) void k_gemm(const AT* __restrict__ A,
                                              const _Float16* __restrict__ WT,
                                              const float* __restrict__ bias,
                                              CT* __restrict__ C,
                                              int M, int N, int K,
                                              float scale,
                                              _Float16* __restrict__ qbT){
    __shared__ _Float16 Al[64*64];
    __shared__ _Float16 Wl[64*64];
    int tid = threadIdx.x; int l = tid & 63; int w = tid >> 6;
    int l15 = l & 15, lq = l >> 4;
    int m0 = blockIdx.y*64, n0 = blockIdx.x*64;
    v4f acc[4] = {};
    float bv[4];
    #pragma unroll
    for (int nt=0;nt<4;nt++) bv[nt] = bias[n0 + nt*16 + l15];
    int srow = tid>>2, sseg = (tid&3)*16;
    for (int k0=0;k0<K;k0+=64){
        if constexpr (sizeof(AT)==4){
            const float* src = (const float*)A + (size_t)(m0+srow)*K + k0 + sseg;
            float4 f0 = *(const float4*)src;
            float4 f1 = *(const float4*)(src+4);
            float4 f2 = *(const float4*)(src+8);
            float4 f3 = *(const float4*)(src+12);
            st8(&Al[swz(srow, sseg)],   cvt8(f0,f1));
            st8(&Al[swz(srow, sseg+8)], cvt8(f2,f3));
        } else {
            const _Float16* src = (const _Float16*)A + (size_t)(m0+srow)*K + k0 + sseg;
            v8h h0 = *(const v8h*)src;
            v8h h1 = *(const v8h*)(src+8);
            st8(&Al[swz(srow, sseg)],   h0);
            st8(&Al[swz(srow, sseg+8)], h1);
        }
        {
            const _Float16* src = WT + (size_t)(n0+srow)*K + k0 + sseg;
            v8h h0 = *(const v8h*)src;
            v8h h1 = *(const v8h*)(src+8);
            st8(&Wl[swz(srow, sseg)],   h0);
            st8(&Wl[swz(srow, sseg+8)], h1);
        }
        __syncthreads();
        #pragma unroll
        for (int kk=0; kk<2; ++kk){
            v8h a = *(const v8h*)&Al[swz(w*16 + l15, kk*32 + lq*8)];
            #pragma unroll
            for (int nt=0;nt<4;nt++){
                v8h b = *(const v8h*)&Wl[swz(nt*16 + l15, kk*32 + lq*8)];
                acc[nt] = MFMA32(a, b, acc[nt]);
            }
        }
        __syncthreads();
    }
    #pragma unroll
    for (int nt=0;nt<4;nt++){
        #pragma unroll
        for (int i=0;i<4;i++){
            int row = m0 + w*16 + lq*4 + i;
            int col = n0 + nt*16 + l15;
            float vfull = (acc[nt][i] + bv[nt])*scale;
            C[(size_t)row*N + col] = (CT)vfull;
            if constexpr (QB){
                int bI = row>>10, t = row&1023;
                qbT[((size_t)t<<12) + (bI<<9) + col] = (_Float16)vfull;
            }
        }
    }
}

// ---------------- fused K+V projection: one A-stage, two MFMA streams --------
__global__ __launch_bounds__(256) void k_gemmkv(const _Float16* __restrict__ A,
                                                const _Float16* __restrict__ WTk,
                                                const _Float16* __restrict__ WTv,
                                                const float* __restrict__ bk,
                                                const float* __restrict__ bv,
                                                _Float16* __restrict__ Ck,
                                                _Float16* __restrict__ Cv){
    __shared__ _Float16 Al[64*64];
    __shared__ _Float16 Wkl[64*64];
    __shared__ _Float16 Wvl[64*64];
    int tid = threadIdx.x; int l = tid & 63; int w = tid >> 6;
    int l15 = l & 15, lq = l >> 4;
    int m0 = blockIdx.y*64, n0 = blockIdx.x*64;
    v4f ak[4] = {}, av[4] = {};
    float bkr[4], bvr[4];
    #pragma unroll
    for (int nt=0;nt<4;nt++){ bkr[nt] = bk[n0 + nt*16 + l15]; bvr[nt] = bv[n0 + nt*16 + l15]; }
    int srow = tid>>2, sseg = (tid&3)*16;
    for (int k0=0;k0<512;k0+=64){
        {
            const _Float16* src = A + (size_t)(m0+srow)*512 + k0 + sseg;
            v8h h0 = *(const v8h*)src;
            v8h h1 = *(const v8h*)(src+8);
            st8(&Al[swz(srow, sseg)],   h0);
            st8(&Al[swz(srow, sseg+8)], h1);
        }
        {
            const _Float16* src = WTk + (size_t)(n0+srow)*512 + k0 + sseg;
            v8h h0 = *(const v8h*)src;
            v8h h1 = *(const v8h*)(src+8);
            st8(&Wkl[swz(srow, sseg)],   h0);
            st8(&Wkl[swz(srow, sseg+8)], h1);
        }
        {
            const _Float16* src = WTv + (size_t)(n0+srow)*512 + k0 + sseg;
            v8h h0 = *(const v8h*)src;
            v8h h1 = *(const v8h*)(src+8);
            st8(&Wvl[swz(srow, sseg)],   h0);
            st8(&Wvl[swz(srow, sseg+8)], h1);
        }
        __syncthreads();
        #pragma unroll
        for (int kk=0; kk<2; ++kk){
            v8h a = *(const v8h*)&Al[swz(w*16 + l15, kk*32 + lq*8)];
            #pragma unroll
            for (int nt=0;nt<4;nt++){
                v8h wk = *(const v8h*)&Wkl[swz(nt*16 + l15, kk*32 + lq*8)];
                v8h wv = *(const v8h*)&Wvl[swz(nt*16 + l15, kk*32 + lq*8)];
                ak[nt] = MFMA32(a, wk, ak[nt]);
                av[nt] = MFMA32(a, wv, av[nt]);
            }
        }
        __syncthreads();
    }
    #pragma unroll
    for (int nt=0;nt<4;nt++){
        #pragma unroll
        for (int i=0;i<4;i++){
            int row = m0 + w*16 + lq*4 + i;
            int col = n0 + nt*16 + l15;
            Ck[(size_t)row*512 + col] = (_Float16)(ak[nt][i] + bkr[nt]);
            Cv[(size_t)row*512 + col] = (_Float16)(av[nt][i] + bvr[nt]);
        }
    }
}

// ---------------- bias v6: LDS-staged streaming ------------------------------
// Sb[t][bh][s] = qb[t,bh,:]·posk[t,s,:], mask folded in the stream-out pass.
// grid 2048 (t = blk>>1, s-half = blk&1), 256 thr (4 waves).
// posk loads: 1 KB contiguous per wave-instr (16 full lines). MFMA B from LDS.
// Output assembled in LDS, streamed as coalesced v8h stores.
__global__ __launch_bounds__(256) void k_bias(const _Float16* __restrict__ qb,
                                              const float* __restrict__ posk,
                                              const int* __restrict__ mask,
                                              _Float16* __restrict__ Sb){
    __shared__ _Float16 Pl[64*64];   // posk chunk [s][d] fp16, swizzled
    __shared__ _Float16 Ol[64*72];   // out tile [bh][s], pad 72
    int t = blockIdx.x >> 1, sh = blockIdx.x & 1;
    int tid = threadIdx.x, l = tid&63, w = tid>>6;
    int l31 = l&31, hi = l>>5;
    int g = w & 1, sg = w >> 1;      // wave's bh-group / s-subgroup
    // A-frags for this wave's bh-group only (rows g*32 + l31)
    v8h aa[4];
    const _Float16* qbt = qb + ((size_t)t<<12);
    #pragma unroll
    for (int k0=0;k0<4;++k0)
        aa[k0] = *(const v8h*)(qbt + (g*32 + l31)*64 + k0*16 + hi*8);

    const float* pkt = posk + ((size_t)t<<16);
    int sbase = sh*512;
    int lrow = (l>>4), lcol = (l&15)*4;      // within-wave load geometry

    // prefetch chunk 0 (fully coalesced: wave-instr = 1 KB contiguous)
    v4f pf[4];
    #pragma unroll
    for (int j=0;j<4;++j)
        pf[j] = *(const v4f*)(pkt + (size_t)(sbase + w*16 + j*4 + lrow)*64 + lcol);

    // stream-out geometry: thread owns bh = tid>>2, 16 s at (tid&3)*16
    int obh = tid>>2;
    int osl = (tid&3)*16;
    int ob  = obh>>3;
    const int* mbase = mask + (((size_t)(ob*Tt + t))<<10);
    _Float16* sbb = Sb + (((size_t)(t*64 + obh))<<10);

    for (int sc=0; sc<8; ++sc){
        int s0 = sbase + sc*64;
        // write prefetched posk to LDS as fp16
        #pragma unroll
        for (int j=0;j<4;++j){
            int rl = w*16 + j*4 + lrow;
            v4h hv; hv[0]=(_Float16)pf[j][0]; hv[1]=(_Float16)pf[j][1];
                    hv[2]=(_Float16)pf[j][2]; hv[3]=(_Float16)pf[j][3];
            *(v4h*)&Pl[swz(rl, lcol)] = hv;
        }
        __syncthreads();
        // prefetch next chunk (lands during MFMA below)
        if (sc < 7){
            #pragma unroll
            for (int j=0;j<4;++j)
                pf[j] = *(const v4f*)(pkt + (size_t)(s0 + 64 + w*16 + j*4 + lrow)*64 + lcol);
        }
        // mask for this chunk's stream-out (issued early)
        int4 mq[4];
        #pragma unroll
        for (int j=0;j<4;++j)
            mq[j] = *(const int4*)(mbase + s0 + osl + j*4);
        // MFMA: B-frags from LDS; this wave covers (g, sg) quadrant
        v8h bfr[4];
        #pragma unroll
        for (int k0=0;k0<4;++k0)
            bfr[k0] = *(v8h*)&Pl[swz(sg*32 + l31, k0*16 + hi*8)];
        v16f acc = {};
        #pragma unroll
        for (int k0=0;k0<4;++k0) acc = MFMA3216(aa[k0], bfr[k0], acc);
        #pragma unroll
        for (int r=0;r<16;++r){
            int bh = g*32 + (r&3) + 4*hi + 8*(r>>2);
            Ol[bh*72 + sg*32 + l31] = (_Float16)acc[r];
        }
        __syncthreads();
        // stream out with mask fold: 16 halfs (32 B) per thread, coalesced
        v8h o0 = *(v8h*)&Ol[obh*72 + osl];
        v8h o1 = *(v8h*)&Ol[obh*72 + osl + 8];
        const _Float16 NEG = (_Float16)(-30000.f);
        int mm[16] = {mq[0].x,mq[0].y,mq[0].z,mq[0].w, mq[1].x,mq[1].y,mq[1].z,mq[1].w,
                      mq[2].x,mq[2].y,mq[2].z,mq[2].w, mq[3].x,mq[3].y,mq[3].z,mq[3].w};
        #pragma unroll
        for (int j=0;j<8;++j){ if(!mm[j]) o0[j]=NEG; if(!mm[8+j]) o1[j]=NEG; }
        *(v8h*)(sbb + s0 + osl)     = o0;
        *(v8h*)(sbb + s0 + osl + 8) = o1;
    }
}

// ---------------- flash: content QK + bias + online softmax + PV -------------
// grid (64 bh, 8 t-tiles of 128), 512 thr. T14 async-stage prefetch.
__global__ __launch_bounds__(512) void k_flash(const _Float16* __restrict__ qs,
                                               const _Float16* __restrict__ kbuf,
                                               const _Float16* __restrict__ vbuf,
                                               const _Float16* __restrict__ Sb,
                                               _Float16* __restrict__ ao){
    __shared__ _Float16 Kl[64*64];    // [s][d] swizzled
    __shared__ _Float16 Vt[64*64];    // [d][s] swizzled
    __shared__ _Float16 Bl[128*64];   // bias chunk then P, [t][s] swizzled
    int bh = blockIdx.x; int b = bh>>3, h = bh&7;
    int t0 = blockIdx.y*128;
    int tid = threadIdx.x, l = tid&63, w = tid>>6, l15 = l&15, lq = l>>4;

    // resident Q A-frags (scaled fp16), rows t0 + w*16 + l15
    v8h qa[2];
    #pragma unroll
    for (int u=0;u<2;++u)
        qa[u] = *(const v8h*)(qs + ((size_t)(b*Tt + t0 + w*16 + l15))*NFf + h*DKk + u*32 + lq*8);

    v4f O[4] = {};
    float mrow[4], lrow[4];
    #pragma unroll
    for (int i=0;i<4;i++){ mrow[i] = -1e30f; lrow[i] = 0.f; }

    // staging geometry
    int kr = tid>>3, kseg = (tid&7)*8;
    int vs = tid&63, vd0 = (tid>>6)*8;
    int br = tid>>2, bhf = (tid&3)*16;
    const _Float16* kbase = kbuf + ((size_t)(b*Tt + kr))*NFf + h*DKk + kseg;
    const _Float16* vbase = vbuf + ((size_t)(b*Tt + vs))*NFf + h*DKk + vd0;
    const _Float16* bbase = Sb + (((size_t)((t0+br)*64 + bh))<<10) + bhf;

    // prefetch chunk 0
    v8h pk = *(const v8h*)kbase;
    v8h pv = *(const v8h*)vbase;
    v8h pb0 = *(const v8h*)bbase;
    v8h pb1 = *((const v8h*)bbase + 1);

    for (int sc=0; sc<16; ++sc){
        // write staged regs to LDS
        st8(&Kl[swz(kr, kseg)], pk);
        #pragma unroll
        for (int j=0;j<8;j++) Vt[swz(vd0+j, vs)] = pv[j];
        st8(&Bl[swz(br, bhf)],   pb0);
        st8(&Bl[swz(br, bhf+8)], pb1);
        __syncthreads();
        // issue next chunk's loads (land during compute below)
        if (sc < 15){
            size_t soff = (size_t)(sc+1)*64;
            pk  = *(const v8h*)(kbase + soff*NFf);
            pv  = *(const v8h*)(vbase + soff*NFf);
            pb0 = *(const v8h*)(bbase + soff);
            pb1 = *((const v8h*)(bbase + soff) + 1);
        }

        v4f sv[4];
        #pragma unroll
        for (int nt=0; nt<4; ++nt){
            v8h kb0 = *(v8h*)&Kl[swz(nt*16+l15, lq*8)];
            v8h kb1 = *(v8h*)&Kl[swz(nt*16+l15, 32+lq*8)];
            v4f a = {};
            a = MFMA32(qa[0], kb0, a);
            a = MFMA32(qa[1], kb1, a);
            int rb = w*16;
            #pragma unroll
            for (int i=0;i<4;i++)
                a[i] += (float)Bl[swz(rb + lq*4 + i, nt*16 + l15)];
            sv[nt] = a;
        }
        // online softmax with defer-max (exact: skipping when no growth is bit-exact)
        float mn[4]; float grow = 0.f;
        #pragma unroll
        for (int i=0;i<4;i++){
            float mx = fmaxf(fmaxf(sv[0][i],sv[1][i]),fmaxf(sv[2][i],sv[3][i]));
            mx = fmaxf(mx, __shfl_xor(mx,1));
            mx = fmaxf(mx, __shfl_xor(mx,2));
            mx = fmaxf(mx, __shfl_xor(mx,4));
            mx = fmaxf(mx, __shfl_xor(mx,8));
            mn[i] = fmaxf(mrow[i], mx);
            grow = fmaxf(grow, mn[i] - mrow[i]);
        }
        if (__any(grow > 0.f)){
            #pragma unroll
            for (int i=0;i<4;i++){
                float rsc = exp2f(mrow[i] - mn[i]);
                mrow[i] = mn[i];
                lrow[i] *= rsc;
                #pragma unroll
                for (int nt=0; nt<4; ++nt) O[nt][i] *= rsc;
            }
        }
        #pragma unroll
        for (int i=0;i<4;i++){
            float ps = 0.f;
            #pragma unroll
            for (int nt=0; nt<4; ++nt){
                float pv2 = exp2f(sv[nt][i] - mrow[i]);
                sv[nt][i] = pv2;
                ps += pv2;
            }
            ps += __shfl_xor(ps,1);
            ps += __shfl_xor(ps,2);
            ps += __shfl_xor(ps,4);
            ps += __shfl_xor(ps,8);
            lrow[i] += ps;
        }
        // write P (fp16) into Bl over this wave's rows
        #pragma unroll
        for (int nt=0;nt<4;++nt){
            #pragma unroll
            for (int i=0;i<4;i++)
                Bl[swz(w*16+lq*4+i, nt*16+l15)] = (_Float16)sv[nt][i];
        }
        // PV: A = P rows (own wave), B = Vt
        {
            v8h pa0 = *(v8h*)&Bl[swz(w*16+l15, lq*8)];
            v8h pa1 = *(v8h*)&Bl[swz(w*16+l15, 32+lq*8)];
            #pragma unroll
            for (int nt=0; nt<4; ++nt){
                v8h vb0 = *(v8h*)&Vt[swz(nt*16+l15, lq*8)];
                v8h vb1 = *(v8h*)&Vt[swz(nt*16+l15, 32+lq*8)];
                O[nt] = MFMA32(pa0, vb0, O[nt]);
                O[nt] = MFMA32(pa1, vb1, O[nt]);
            }
        }
        __syncthreads();
    }

    #pragma unroll
    for (int i=0;i<4;i++){
        float lr = lrow[i];
        float rl = (lr > 0.f) ? 1.f/lr : 0.f;
        int row = t0 + w*16 + lq*4 + i;
        #pragma unroll
        for (int nt=0; nt<4; ++nt)
            ao[((size_t)(b*Tt + row))*NFf + h*DKk + nt*16 + l15] = (_Float16)(O[nt][i]*rl);
    }
}

// ---------------- launch ----------------
extern "C" void kernel_launch(void* const* d_in, const int* in_sizes, int n_in,
                              void* d_out, int out_size, void* d_ws, size_t ws_size,
                              hipStream_t stream) {
    const float* x       = (const float*)d_in[0];
    const float* cond    = (const float*)d_in[1];
    const float* pos_k   = (const float*)d_in[2];
    const int*   mask    = (const int*)  d_in[3];
    const float* ln_g    = (const float*)d_in[4];
    const float* ln_b    = (const float*)d_in[5];
    const float* Wq      = (const float*)d_in[6];
    const float* bq      = (const float*)d_in[7];
    const float* Wk      = (const float*)d_in[8];
    const float* bk      = (const float*)d_in[9];
    const float* Wv      = (const float*)d_in[10];
    const float* bv      = (const float*)d_in[11];
    const float* Wo      = (const float*)d_in[12];
    const float* bo      = (const float*)d_in[13];
    const float* Wc      = (const float*)d_in[14];
    const float* bc      = (const float*)d_in[15];
    float* out = (float*)d_out;

    char* base = (char*)d_ws;
    const size_t OFF_S    = 0;                       // 134217728 B fp16 Sb
    const size_t OFF_XN   = 134217728;
    const size_t OFF_Q    = OFF_XN  + 8388608;
    const size_t OFF_QB   = OFF_Q   + 8388608;
    const size_t OFF_K    = OFF_QB  + 8388608;
    const size_t OFF_V    = OFF_K   + 8388608;
    const size_t OFF_AO   = OFF_V   + 8388608;
    const size_t OFF_WKT  = OFF_AO  + 8388608;       // 524288
    const size_t OFF_WVT  = OFF_WKT + 524288;
    const size_t OFF_WOT  = OFF_WVT + 524288;
    const size_t OFF_WCQT = OFF_WOT + 524288;        // 262144
    const size_t OFF_BCQ  = OFF_WCQT + 262144;

    _Float16* xn    = (_Float16*)(base + OFF_XN);
    _Float16* qbuf  = (_Float16*)(base + OFF_Q);
    _Float16* qb    = (_Float16*)(base + OFF_QB);
    _Float16* kb    = (_Float16*)(base + OFF_K);
    _Float16* vb    = (_Float16*)(base + OFF_V);
    _Float16* ao    = (_Float16*)(base + OFF_AO);
    _Float16* Sb    = (_Float16*)(base + OFF_S);
    _Float16* WkT   = (_Float16*)(base + OFF_WKT);
    _Float16* WvT   = (_Float16*)(base + OFF_WVT);
    _Float16* WoT   = (_Float16*)(base + OFF_WOT);
    _Float16* wcqT  = (_Float16*)(base + OFF_WCQT);
    float*    bcq   = (float*)(base + OFF_BCQ);

    k_ln<<<dim3(Bb*Tt), dim3(256), 0, stream>>>(x, ln_g, ln_b, xn);
    k_wT<<<dim3(8,8), dim3(256), 0, stream>>>(Wk, WkT);
    k_wT<<<dim3(8,8), dim3(256), 0, stream>>>(Wv, WvT);
    k_wT<<<dim3(8,8), dim3(256), 0, stream>>>(Wo, WoT);
    k_wcq<<<dim3(32), dim3(512), 0, stream>>>(Wc, Wq, wcqT);
    k_bcq<<<dim3(1), dim3(512), 0, stream>>>(bc, Wq, bq, bcq);

    // q projection: writes scaled qbuf AND scaled transposed qb
    k_gemm<float,_Float16,true><<<dim3(8,128), dim3(256), 0, stream>>>(cond, wcqT, bcq, qbuf, Bb*Tt, 512, 256, SCQ, qb);
    // fused K+V projection
    k_gemmkv<<<dim3(8,128), dim3(256), 0, stream>>>(xn, WkT, WvT, bk, bv, kb, vb);

    k_bias<<<dim3(2048), dim3(256), 0, stream>>>(qb, pos_k, mask, Sb);
    k_flash<<<dim3(64,8), dim3(512), 0, stream>>>(qbuf, kb, vb, Sb, ao);

    k_gemm<_Float16,float,false><<<dim3(8,128), dim3(256), 0, stream>>>(ao, WoT, bo, out, Bb*Tt, 512, 512, 1.f, nullptr);
}

// Round 12
// 331.873 us; speedup vs baseline: 1.1789x; 1.0701x over previous
//
#include <hip/hip_runtime.h>

// ---------------- problem constants ----------------
#define Bb 8
#define Tt 1024
#define Hh 8
#define DKk 64
#define NFf 512
#define DCc 256

typedef _Float16 v2h __attribute__((ext_vector_type(2)));
typedef _Float16 v4h __attribute__((ext_vector_type(4)));
typedef _Float16 v8h __attribute__((ext_vector_type(8)));
typedef float    v4f __attribute__((ext_vector_type(4)));
typedef float    v16f __attribute__((ext_vector_type(16)));

#define MFMA32(a,b,c) __builtin_amdgcn_mfma_f32_16x16x32_f16((a),(b),(c),0,0,0)
#define MFMA3216(a,b,c) __builtin_amdgcn_mfma_f32_32x32x16_f16((a),(b),(c),0,0,0)

// scale folded into q: 1/sqrt(64) * log2(e)  (scores live in log2 domain)
#define SCQ 0.1803368801111f

__device__ inline void st8(_Float16* dst, v8h x){
    *(v4h*)dst     = __builtin_shufflevector(x,x,0,1,2,3);
    *(v4h*)(dst+4) = __builtin_shufflevector(x,x,4,5,6,7);
}

__device__ inline v8h cvt8(float4 a, float4 b){
    v8h r;
    r[0]=(_Float16)a.x; r[1]=(_Float16)a.y; r[2]=(_Float16)a.z; r[3]=(_Float16)a.w;
    r[4]=(_Float16)b.x; r[5]=(_Float16)b.y; r[6]=(_Float16)b.z; r[7]=(_Float16)b.w;
    return r;
}

// XOR swizzle for [R][64] half LDS tiles; keeps 8-half granularity
__device__ inline int swz(int r, int c){ return (r*64 + c) ^ ((r&7)<<3); }

// ---------------- LayerNorm: x (8192,512) fp32 -> xn fp16 ----------------
__global__ __launch_bounds__(256) void k_ln(const float* __restrict__ x,
                                            const float* __restrict__ g,
                                            const float* __restrict__ be,
                                            _Float16* __restrict__ xn){
    int row = blockIdx.x; int tid = threadIdx.x;
    const float* xr = x + (size_t)row*512;
    float2 v = reinterpret_cast<const float2*>(xr)[tid];
    float s = v.x + v.y, sq = v.x*v.x + v.y*v.y;
    for (int off=32; off; off>>=1){ s += __shfl_down(s, off); sq += __shfl_down(sq, off); }
    __shared__ float ws_[4], wq_[4];
    __shared__ float mu_s, rs_s;
    int wid = tid>>6, lid = tid&63;
    if (lid==0){ ws_[wid]=s; wq_[wid]=sq; }
    __syncthreads();
    if (tid==0){
        float S=0,Q=0;
        for(int i=0;i<4;i++){S+=ws_[i];Q+=wq_[i];}
        float mu = S*(1.f/512.f);
        float var = Q*(1.f/512.f)-mu*mu;
        mu_s=mu; rs_s=rsqrtf(var+1e-5f);
    }
    __syncthreads();
    float mu=mu_s, rs=rs_s;
    float2 gv = reinterpret_cast<const float2*>(g)[tid];
    float2 bv = reinterpret_cast<const float2*>(be)[tid];
    v2h o; o[0] = (_Float16)((v.x-mu)*rs*gv.x + bv.x);
           o[1] = (_Float16)((v.y-mu)*rs*gv.y + bv.y);
    reinterpret_cast<v2h*>(xn + (size_t)row*512)[tid] = o;
}

// ---------------- weight transpose: W (512,512) fp32 -> WT (N,K) fp16 --------
__global__ __launch_bounds__(256) void k_wT(const float* __restrict__ W,
                                            _Float16* __restrict__ WT){
    __shared__ float tile[64][65];
    int bx = blockIdx.x*64, by = blockIdx.y*64;   // bx: n-base, by: k-base
    int tid = threadIdx.x, c = tid&63;
    for (int r = tid>>6; r<64; r+=4) tile[r][c] = W[(size_t)(by+r)*512 + bx + c];
    __syncthreads();
    for (int n = tid>>6; n<64; n+=4) WT[(size_t)(bx+n)*512 + by + c] = (_Float16)tile[c][n];
}

// ---------------- wcqT = (Wc @ Wq)^T fp16 [512][256] ----------------
__global__ __launch_bounds__(512) void k_wcq(const float* __restrict__ Wc,
                                             const float* __restrict__ Wq,
                                             _Float16* __restrict__ wcqT){
    __shared__ float wc[8][512];
    int i0 = blockIdx.x*8; int tid = threadIdx.x;
    for (int r=0;r<8;r++) wc[r][tid] = Wc[(size_t)(i0+r)*512 + tid];
    __syncthreads();
    float acc[8] = {0,0,0,0,0,0,0,0};
    for (int m=0;m<512;m++){
        float wq = Wq[(size_t)m*512+tid];
        #pragma unroll
        for (int r=0;r<8;r++) acc[r] += wc[r][m]*wq;
    }
    for (int r=0;r<8;r++) wcqT[(size_t)tid*256 + i0 + r] = (_Float16)acc[r];
}

// ---------------- bcq = bc @ Wq + bq ----------------
__global__ __launch_bounds__(512) void k_bcq(const float* __restrict__ bc,
                                             const float* __restrict__ Wq,
                                             const float* __restrict__ bq,
                                             float* __restrict__ bcq){
    int j = threadIdx.x;
    float a = bq[j];
    for (int m=0;m<512;m++) a += bc[m]*Wq[(size_t)m*512+j];
    bcq[j] = a;
}

// ---------------- GEMM v2: C(M,N) = (A(M,K) @ WT(N,K)^T + bias)*scale --------
template<typename AT, typename CT, bool QB>
__global__ __launch_bounds__(256) void k_gemm(const AT* __restrict__ A,
                                              const _Float16* __restrict__ WT,
                                              const float* __restrict__ bias,
                                              CT* __restrict__ C,
                                              int M, int N, int K,
                                              float scale,
                                              _Float16* __restrict__ qbT){
    __shared__ _Float16 Al[64*64];
    __shared__ _Float16 Wl[64*64];
    int tid = threadIdx.x; int l = tid & 63; int w = tid >> 6;
    int l15 = l & 15, lq = l >> 4;
    int m0 = blockIdx.y*64, n0 = blockIdx.x*64;
    v4f acc[4] = {};
    float bv[4];
    #pragma unroll
    for (int nt=0;nt<4;nt++) bv[nt] = bias[n0 + nt*16 + l15];
    int srow = tid>>2, sseg = (tid&3)*16;
    for (int k0=0;k0<K;k0+=64){
        if constexpr (sizeof(AT)==4){
            const float* src = (const float*)A + (size_t)(m0+srow)*K + k0 + sseg;
            float4 f0 = *(const float4*)src;
            float4 f1 = *(const float4*)(src+4);
            float4 f2 = *(const float4*)(src+8);
            float4 f3 = *(const float4*)(src+12);
            st8(&Al[swz(srow, sseg)],   cvt8(f0,f1));
            st8(&Al[swz(srow, sseg+8)], cvt8(f2,f3));
        } else {
            const _Float16* src = (const _Float16*)A + (size_t)(m0+srow)*K + k0 + sseg;
            v8h h0 = *(const v8h*)src;
            v8h h1 = *(const v8h*)(src+8);
            st8(&Al[swz(srow, sseg)],   h0);
            st8(&Al[swz(srow, sseg+8)], h1);
        }
        {
            const _Float16* src = WT + (size_t)(n0+srow)*K + k0 + sseg;
            v8h h0 = *(const v8h*)src;
            v8h h1 = *(const v8h*)(src+8);
            st8(&Wl[swz(srow, sseg)],   h0);
            st8(&Wl[swz(srow, sseg+8)], h1);
        }
        __syncthreads();
        #pragma unroll
        for (int kk=0; kk<2; ++kk){
            v8h a = *(const v8h*)&Al[swz(w*16 + l15, kk*32 + lq*8)];
            #pragma unroll
            for (int nt=0;nt<4;nt++){
                v8h b = *(const v8h*)&Wl[swz(nt*16 + l15, kk*32 + lq*8)];
                acc[nt] = MFMA32(a, b, acc[nt]);
            }
        }
        __syncthreads();
    }
    #pragma unroll
    for (int nt=0;nt<4;nt++){
        #pragma unroll
        for (int i=0;i<4;i++){
            int row = m0 + w*16 + lq*4 + i;
            int col = n0 + nt*16 + l15;
            float vfull = (acc[nt][i] + bv[nt])*scale;
            C[(size_t)row*N + col] = (CT)vfull;
            if constexpr (QB){
                int bI = row>>10, t = row&1023;
                qbT[((size_t)t<<12) + (bI<<9) + col] = (_Float16)vfull;
            }
        }
    }
}

// ---------------- fused K+V projection: one A-stage, two MFMA streams --------
__global__ __launch_bounds__(256) void k_gemmkv(const _Float16* __restrict__ A,
                                                const _Float16* __restrict__ WTk,
                                                const _Float16* __restrict__ WTv,
                                                const float* __restrict__ bk,
                                                const float* __restrict__ bv,
                                                _Float16* __restrict__ Ck,
                                                _Float16* __restrict__ Cv){
    __shared__ _Float16 Al[64*64];
    __shared__ _Float16 Wkl[64*64];
    __shared__ _Float16 Wvl[64*64];
    int tid = threadIdx.x; int l = tid & 63; int w = tid >> 6;
    int l15 = l & 15, lq = l >> 4;
    int m0 = blockIdx.y*64, n0 = blockIdx.x*64;
    v4f ak[4] = {}, av[4] = {};
    float bkr[4], bvr[4];
    #pragma unroll
    for (int nt=0;nt<4;nt++){ bkr[nt] = bk[n0 + nt*16 + l15]; bvr[nt] = bv[n0 + nt*16 + l15]; }
    int srow = tid>>2, sseg = (tid&3)*16;
    for (int k0=0;k0<512;k0+=64){
        {
            const _Float16* src = A + (size_t)(m0+srow)*512 + k0 + sseg;
            v8h h0 = *(const v8h*)src;
            v8h h1 = *(const v8h*)(src+8);
            st8(&Al[swz(srow, sseg)],   h0);
            st8(&Al[swz(srow, sseg+8)], h1);
        }
        {
            const _Float16* src = WTk + (size_t)(n0+srow)*512 + k0 + sseg;
            v8h h0 = *(const v8h*)src;
            v8h h1 = *(const v8h*)(src+8);
            st8(&Wkl[swz(srow, sseg)],   h0);
            st8(&Wkl[swz(srow, sseg+8)], h1);
        }
        {
            const _Float16* src = WTv + (size_t)(n0+srow)*512 + k0 + sseg;
            v8h h0 = *(const v8h*)src;
            v8h h1 = *(const v8h*)(src+8);
            st8(&Wvl[swz(srow, sseg)],   h0);
            st8(&Wvl[swz(srow, sseg+8)], h1);
        }
        __syncthreads();
        #pragma unroll
        for (int kk=0; kk<2; ++kk){
            v8h a = *(const v8h*)&Al[swz(w*16 + l15, kk*32 + lq*8)];
            #pragma unroll
            for (int nt=0;nt<4;nt++){
                v8h wk = *(const v8h*)&Wkl[swz(nt*16 + l15, kk*32 + lq*8)];
                v8h wv = *(const v8h*)&Wvl[swz(nt*16 + l15, kk*32 + lq*8)];
                ak[nt] = MFMA32(a, wk, ak[nt]);
                av[nt] = MFMA32(a, wv, av[nt]);
            }
        }
        __syncthreads();
    }
    #pragma unroll
    for (int nt=0;nt<4;nt++){
        #pragma unroll
        for (int i=0;i<4;i++){
            int row = m0 + w*16 + lq*4 + i;
            int col = n0 + nt*16 + l15;
            Ck[(size_t)row*512 + col] = (_Float16)(ak[nt][i] + bkr[nt]);
            Cv[(size_t)row*512 + col] = (_Float16)(av[nt][i] + bvr[nt]);
        }
    }
}

// ---------------- bias v6: LDS-staged streaming ------------------------------
__global__ __launch_bounds__(256) void k_bias(const _Float16* __restrict__ qb,
                                              const float* __restrict__ posk,
                                              const int* __restrict__ mask,
                                              _Float16* __restrict__ Sb){
    __shared__ _Float16 Pl[64*64];   // posk chunk [s][d] fp16, swizzled
    __shared__ _Float16 Ol[64*72];   // out tile [bh][s], pad 72
    int t = blockIdx.x >> 1, sh = blockIdx.x & 1;
    int tid = threadIdx.x, l = tid&63, w = tid>>6;
    int l31 = l&31, hi = l>>5;
    int g = w & 1, sg = w >> 1;      // wave's bh-group / s-subgroup
    v8h aa[4];
    const _Float16* qbt = qb + ((size_t)t<<12);
    #pragma unroll
    for (int k0=0;k0<4;++k0)
        aa[k0] = *(const v8h*)(qbt + (g*32 + l31)*64 + k0*16 + hi*8);

    const float* pkt = posk + ((size_t)t<<16);
    int sbase = sh*512;
    int lrow = (l>>4), lcol = (l&15)*4;      // within-wave load geometry

    v4f pf[4];
    #pragma unroll
    for (int j=0;j<4;++j)
        pf[j] = *(const v4f*)(pkt + (size_t)(sbase + w*16 + j*4 + lrow)*64 + lcol);

    int obh = tid>>2;
    int osl = (tid&3)*16;
    int ob  = obh>>3;
    const int* mbase = mask + (((size_t)(ob*Tt + t))<<10);
    _Float16* sbb = Sb + (((size_t)(t*64 + obh))<<10);

    for (int sc=0; sc<8; ++sc){
        int s0 = sbase + sc*64;
        #pragma unroll
        for (int j=0;j<4;++j){
            int rl = w*16 + j*4 + lrow;
            v4h hv; hv[0]=(_Float16)pf[j][0]; hv[1]=(_Float16)pf[j][1];
                    hv[2]=(_Float16)pf[j][2]; hv[3]=(_Float16)pf[j][3];
            *(v4h*)&Pl[swz(rl, lcol)] = hv;
        }
        __syncthreads();
        if (sc < 7){
            #pragma unroll
            for (int j=0;j<4;++j)
                pf[j] = *(const v4f*)(pkt + (size_t)(s0 + 64 + w*16 + j*4 + lrow)*64 + lcol);
        }
        int4 mq[4];
        #pragma unroll
        for (int j=0;j<4;++j)
            mq[j] = *(const int4*)(mbase + s0 + osl + j*4);
        v8h bfr[4];
        #pragma unroll
        for (int k0=0;k0<4;++k0)
            bfr[k0] = *(v8h*)&Pl[swz(sg*32 + l31, k0*16 + hi*8)];
        v16f acc = {};
        #pragma unroll
        for (int k0=0;k0<4;++k0) acc = MFMA3216(aa[k0], bfr[k0], acc);
        #pragma unroll
        for (int r=0;r<16;++r){
            int bh = g*32 + (r&3) + 4*hi + 8*(r>>2);
            Ol[bh*72 + sg*32 + l31] = (_Float16)acc[r];
        }
        __syncthreads();
        v8h o0 = *(v8h*)&Ol[obh*72 + osl];
        v8h o1 = *(v8h*)&Ol[obh*72 + osl + 8];
        const _Float16 NEG = (_Float16)(-30000.f);
        int mm[16] = {mq[0].x,mq[0].y,mq[0].z,mq[0].w, mq[1].x,mq[1].y,mq[1].z,mq[1].w,
                      mq[2].x,mq[2].y,mq[2].z,mq[2].w, mq[3].x,mq[3].y,mq[3].z,mq[3].w};
        #pragma unroll
        for (int j=0;j<8;++j){ if(!mm[j]) o0[j]=NEG; if(!mm[8+j]) o1[j]=NEG; }
        *(v8h*)(sbb + s0 + osl)     = o0;
        *(v8h*)(sbb + s0 + osl + 8) = o1;
    }
}

// ---------------- flash v3: swapped QK (lane-local rows) ---------------------
// grid (64 bh, 8 t-tiles of 128), 512 thr. S = mfma(K, Q): col = t, row = s.
// Each lane owns ONE t-row's 16 s-values per chunk -> in-register reductions.
__global__ __launch_bounds__(512) void k_flash(const _Float16* __restrict__ qs,
                                               const _Float16* __restrict__ kbuf,
                                               const _Float16* __restrict__ vbuf,
                                               const _Float16* __restrict__ Sb,
                                               _Float16* __restrict__ ao){
    __shared__ _Float16 Kl[64*64];    // [s][d] swizzled
    __shared__ _Float16 Vt[64*64];    // [d][s] swizzled
    __shared__ _Float16 Bl[128*64];   // bias chunk then P, [t][s] swizzled
    int bh = blockIdx.x; int b = bh>>3, h = bh&7;
    int t0 = blockIdx.y*128;
    int tid = threadIdx.x, l = tid&63, w = tid>>6, l15 = l&15, lq = l>>4;

    // resident Q A-frags (scaled fp16), rows t0 + w*16 + l15
    v8h qa[2];
    #pragma unroll
    for (int u=0;u<2;++u)
        qa[u] = *(const v8h*)(qs + ((size_t)(b*Tt + t0 + w*16 + l15))*NFf + h*DKk + u*32 + lq*8);

    v4f O[4] = {};
    float m_l = -1e30f, l_l = 0.f;    // online stats for t-row = t0 + w*16 + l15

    // staging geometry
    int kr = tid>>3, kseg = (tid&7)*8;
    int vs = tid&63, vd0 = (tid>>6)*8;
    int br = tid>>2, bhf = (tid&3)*16;
    const _Float16* kbase = kbuf + ((size_t)(b*Tt + kr))*NFf + h*DKk + kseg;
    const _Float16* vbase = vbuf + ((size_t)(b*Tt + vs))*NFf + h*DKk + vd0;
    const _Float16* bbase = Sb + (((size_t)((t0+br)*64 + bh))<<10) + bhf;

    // prefetch chunk 0
    v8h pk = *(const v8h*)kbase;
    v8h pv = *(const v8h*)vbase;
    v8h pb0 = *(const v8h*)bbase;
    v8h pb1 = *((const v8h*)bbase + 1);

    for (int sc=0; sc<16; ++sc){
        st8(&Kl[swz(kr, kseg)], pk);
        #pragma unroll
        for (int j=0;j<8;j++) Vt[swz(vd0+j, vs)] = pv[j];
        st8(&Bl[swz(br, bhf)],   pb0);
        st8(&Bl[swz(br, bhf+8)], pb1);
        __syncthreads();
        if (sc < 15){
            size_t soff = (size_t)(sc+1)*64;
            pk  = *(const v8h*)(kbase + soff*NFf);
            pv  = *(const v8h*)(vbase + soff*NFf);
            pb0 = *(const v8h*)(bbase + soff);
            pb1 = *((const v8h*)(bbase + soff) + 1);
        }

        // QK^T swapped: A = K rows (s), B = Q rows (t). C: col = t (l15),
        // row = s = nt*16 + lq*4 + i. Bias is contiguous in i -> v4h.
        v4f sv[4];
        #pragma unroll
        for (int nt=0; nt<4; ++nt){
            v8h kb0 = *(v8h*)&Kl[swz(nt*16+l15, lq*8)];
            v8h kb1 = *(v8h*)&Kl[swz(nt*16+l15, 32+lq*8)];
            v4f a = {};
            a = MFMA32(kb0, qa[0], a);
            a = MFMA32(kb1, qa[1], a);
            v4h bl4 = *(v4h*)&Bl[swz(w*16 + l15, nt*16 + lq*4)];
            #pragma unroll
            for (int i=0;i<4;i++) a[i] += (float)bl4[i];
            sv[nt] = a;
        }
        // per-lane online softmax: 16 values of one t-row; reduce over lq (2 hops)
        float mx = fmaxf(fmaxf(fmaxf(sv[0][0],sv[0][1]),fmaxf(sv[0][2],sv[0][3])),
                   fmaxf(fmaxf(fmaxf(sv[1][0],sv[1][1]),fmaxf(sv[1][2],sv[1][3])),
                   fmaxf(fmaxf(fmaxf(sv[2][0],sv[2][1]),fmaxf(sv[2][2],sv[2][3])),
                         fmaxf(fmaxf(sv[3][0],sv[3][1]),fmaxf(sv[3][2],sv[3][3])))));
        mx = fmaxf(mx, __shfl_xor(mx,16));
        mx = fmaxf(mx, __shfl_xor(mx,32));
        float mn = fmaxf(m_l, mx);
        if (__any(mn - m_l > 0.f)){
            float rsc = exp2f(m_l - mn);
            m_l = mn; l_l *= rsc;
            float rscB[4];
            #pragma unroll
            for (int i=0;i<4;i++) rscB[i] = __shfl(rsc, lq*4+i);
            #pragma unroll
            for (int nt=0; nt<4; ++nt)
                #pragma unroll
                for (int i=0;i<4;i++) O[nt][i] *= rscB[i];
        }
        float ps = 0.f;
        #pragma unroll
        for (int nt=0; nt<4; ++nt){
            v4h ph;
            #pragma unroll
            for (int i=0;i<4;i++){
                float p = exp2f(sv[nt][i] - m_l);
                ph[i] = (_Float16)p;
                ps += p;
            }
            *(v4h*)&Bl[swz(w*16 + l15, nt*16 + lq*4)] = ph;
        }
        ps += __shfl_xor(ps,16);
        ps += __shfl_xor(ps,32);
        l_l += ps;
        // PV: A = P rows (own wave), B = Vt  (unchanged orientation)
        {
            v8h pa0 = *(v8h*)&Bl[swz(w*16+l15, lq*8)];
            v8h pa1 = *(v8h*)&Bl[swz(w*16+l15, 32+lq*8)];
            #pragma unroll
            for (int nt=0; nt<4; ++nt){
                v8h vb0 = *(v8h*)&Vt[swz(nt*16+l15, lq*8)];
                v8h vb1 = *(v8h*)&Vt[swz(nt*16+l15, 32+lq*8)];
                O[nt] = MFMA32(pa0, vb0, O[nt]);
                O[nt] = MFMA32(pa1, vb1, O[nt]);
            }
        }
        __syncthreads();
    }

    float rl = (l_l > 0.f) ? 1.f/l_l : 0.f;
    float rlB[4];
    #pragma unroll
    for (int i=0;i<4;i++) rlB[i] = __shfl(rl, lq*4+i);
    #pragma unroll
    for (int i=0;i<4;i++){
        int row = t0 + w*16 + lq*4 + i;
        #pragma unroll
        for (int nt=0; nt<4; ++nt)
            ao[((size_t)(b*Tt + row))*NFf + h*DKk + nt*16 + l15] = (_Float16)(O[nt][i]*rlB[i]);
    }
}

// ---------------- launch ----------------
extern "C" void kernel_launch(void* const* d_in, const int* in_sizes, int n_in,
                              void* d_out, int out_size, void* d_ws, size_t ws_size,
                              hipStream_t stream) {
    const float* x       = (const float*)d_in[0];
    const float* cond    = (const float*)d_in[1];
    const float* pos_k   = (const float*)d_in[2];
    const int*   mask    = (const int*)  d_in[3];
    const float* ln_g    = (const float*)d_in[4];
    const float* ln_b    = (const float*)d_in[5];
    const float* Wq      = (const float*)d_in[6];
    const float* bq      = (const float*)d_in[7];
    const float* Wk      = (const float*)d_in[8];
    const float* bk      = (const float*)d_in[9];
    const float* Wv      = (const float*)d_in[10];
    const float* bv      = (const float*)d_in[11];
    const float* Wo      = (const float*)d_in[12];
    const float* bo      = (const float*)d_in[13];
    const float* Wc      = (const float*)d_in[14];
    const float* bc      = (const float*)d_in[15];
    float* out = (float*)d_out;

    char* base = (char*)d_ws;
    const size_t OFF_S    = 0;                       // 134217728 B fp16 Sb
    const size_t OFF_XN   = 134217728;
    const size_t OFF_Q    = OFF_XN  + 8388608;
    const size_t OFF_QB   = OFF_Q   + 8388608;
    const size_t OFF_K    = OFF_QB  + 8388608;
    const size_t OFF_V    = OFF_K   + 8388608;
    const size_t OFF_AO   = OFF_V   + 8388608;
    const size_t OFF_WKT  = OFF_AO  + 8388608;       // 524288
    const size_t OFF_WVT  = OFF_WKT + 524288;
    const size_t OFF_WOT  = OFF_WVT + 524288;
    const size_t OFF_WCQT = OFF_WOT + 524288;        // 262144
    const size_t OFF_BCQ  = OFF_WCQT + 262144;

    _Float16* xn    = (_Float16*)(base + OFF_XN);
    _Float16* qbuf  = (_Float16*)(base + OFF_Q);
    _Float16* qb    = (_Float16*)(base + OFF_QB);
    _Float16* kb    = (_Float16*)(base + OFF_K);
    _Float16* vb    = (_Float16*)(base + OFF_V);
    _Float16* ao    = (_Float16*)(base + OFF_AO);
    _Float16* Sb    = (_Float16*)(base + OFF_S);
    _Float16* WkT   = (_Float16*)(base + OFF_WKT);
    _Float16* WvT   = (_Float16*)(base + OFF_WVT);
    _Float16* WoT   = (_Float16*)(base + OFF_WOT);
    _Float16* wcqT  = (_Float16*)(base + OFF_WCQT);
    float*    bcq   = (float*)(base + OFF_BCQ);

    k_ln<<<dim3(Bb*Tt), dim3(256), 0, stream>>>(x, ln_g, ln_b, xn);
    k_wT<<<dim3(8,8), dim3(256), 0, stream>>>(Wk, WkT);
    k_wT<<<dim3(8,8), dim3(256), 0, stream>>>(Wv, WvT);
    k_wT<<<dim3(8,8), dim3(256), 0, stream>>>(Wo, WoT);
    k_wcq<<<dim3(32), dim3(512), 0, stream>>>(Wc, Wq, wcqT);
    k_bcq<<<dim3(1), dim3(512), 0, stream>>>(bc, Wq, bq, bcq);

    // q projection: writes scaled qbuf AND scaled transposed qb
    k_gemm<float,_Float16,true><<<dim3(8,128), dim3(256), 0, stream>>>(cond, wcqT, bcq, qbuf, Bb*Tt, 512, 256, SCQ, qb);
    // fused K+V projection
    k_gemmkv<<<dim3(8,128), dim3(256), 0, stream>>>(xn, WkT, WvT, bk, bv, kb, vb);

    k_bias<<<dim3(2048), dim3(256), 0, stream>>>(qb, pos_k, mask, Sb);
    k_flash<<<dim3(64,8), dim3(512), 0, stream>>>(qbuf, kb, vb, Sb, ao);

    k_gemm<_Float16,float,false><<<dim3(8,128), dim3(256), 0, stream>>>(ao, WoT, bo, out, Bb*Tt, 512, 512, 1.f, nullptr);
}

// Round 13
// 310.334 us; speedup vs baseline: 1.2607x; 1.0694x over previous
//
#include <hip/hip_runtime.h>

// ---------------- problem constants ----------------
#define Bb 8
#define Tt 1024
#define Hh 8
#define DKk 64
#define NFf 512
#define DCc 256

typedef _Float16 v2h __attribute__((ext_vector_type(2)));
typedef _Float16 v4h __attribute__((ext_vector_type(4)));
typedef _Float16 v8h __attribute__((ext_vector_type(8)));
typedef float    v4f __attribute__((ext_vector_type(4)));
typedef float    v16f __attribute__((ext_vector_type(16)));

#define MFMA32(a,b,c) __builtin_amdgcn_mfma_f32_16x16x32_f16((a),(b),(c),0,0,0)
#define MFMA3216(a,b,c) __builtin_amdgcn_mfma_f32_32x32x16_f16((a),(b),(c),0,0,0)

// scale folded into q: 1/sqrt(64) * log2(e)  (scores live in log2 domain)
#define SCQ 0.1803368801111f

__device__ inline void st8(_Float16* dst, v8h x){
    *(v4h*)dst     = __builtin_shufflevector(x,x,0,1,2,3);
    *(v4h*)(dst+4) = __builtin_shufflevector(x,x,4,5,6,7);
}

__device__ inline v8h cvt8(float4 a, float4 b){
    v8h r;
    r[0]=(_Float16)a.x; r[1]=(_Float16)a.y; r[2]=(_Float16)a.z; r[3]=(_Float16)a.w;
    r[4]=(_Float16)b.x; r[5]=(_Float16)b.y; r[6]=(_Float16)b.z; r[7]=(_Float16)b.w;
    return r;
}

// XOR swizzle for [R][64] half LDS tiles; keeps 8-half granularity
__device__ inline int swz(int r, int c){ return (r*64 + c) ^ ((r&7)<<3); }

// ---------------- LayerNorm: x (8192,512) fp32 -> xn fp16 ----------------
__global__ __launch_bounds__(256) void k_ln(const float* __restrict__ x,
                                            const float* __restrict__ g,
                                            const float* __restrict__ be,
                                            _Float16* __restrict__ xn){
    int row = blockIdx.x; int tid = threadIdx.x;
    const float* xr = x + (size_t)row*512;
    float2 v = reinterpret_cast<const float2*>(xr)[tid];
    float s = v.x + v.y, sq = v.x*v.x + v.y*v.y;
    for (int off=32; off; off>>=1){ s += __shfl_down(s, off); sq += __shfl_down(sq, off); }
    __shared__ float ws_[4], wq_[4];
    __shared__ float mu_s, rs_s;
    int wid = tid>>6, lid = tid&63;
    if (lid==0){ ws_[wid]=s; wq_[wid]=sq; }
    __syncthreads();
    if (tid==0){
        float S=0,Q=0;
        for(int i=0;i<4;i++){S+=ws_[i];Q+=wq_[i];}
        float mu = S*(1.f/512.f);
        float var = Q*(1.f/512.f)-mu*mu;
        mu_s=mu; rs_s=rsqrtf(var+1e-5f);
    }
    __syncthreads();
    float mu=mu_s, rs=rs_s;
    float2 gv = reinterpret_cast<const float2*>(g)[tid];
    float2 bv = reinterpret_cast<const float2*>(be)[tid];
    v2h o; o[0] = (_Float16)((v.x-mu)*rs*gv.x + bv.x);
           o[1] = (_Float16)((v.y-mu)*rs*gv.y + bv.y);
    reinterpret_cast<v2h*>(xn + (size_t)row*512)[tid] = o;
}

// ---------------- weight transpose: W (512,512) fp32 -> WT (N,K) fp16 --------
__global__ __launch_bounds__(256) void k_wT(const float* __restrict__ W,
                                            _Float16* __restrict__ WT){
    __shared__ float tile[64][65];
    int bx = blockIdx.x*64, by = blockIdx.y*64;   // bx: n-base, by: k-base
    int tid = threadIdx.x, c = tid&63;
    for (int r = tid>>6; r<64; r+=4) tile[r][c] = W[(size_t)(by+r)*512 + bx + c];
    __syncthreads();
    for (int n = tid>>6; n<64; n+=4) WT[(size_t)(bx+n)*512 + by + c] = (_Float16)tile[c][n];
}

// ---------------- wcqT = (Wc @ Wq)^T fp16 [512][256] ----------------
__global__ __launch_bounds__(512) void k_wcq(const float* __restrict__ Wc,
                                             const float* __restrict__ Wq,
                                             _Float16* __restrict__ wcqT){
    __shared__ float wc[8][512];
    int i0 = blockIdx.x*8; int tid = threadIdx.x;
    for (int r=0;r<8;r++) wc[r][tid] = Wc[(size_t)(i0+r)*512 + tid];
    __syncthreads();
    float acc[8] = {0,0,0,0,0,0,0,0};
    for (int m=0;m<512;m++){
        float wq = Wq[(size_t)m*512+tid];
        #pragma unroll
        for (int r=0;r<8;r++) acc[r] += wc[r][m]*wq;
    }
    for (int r=0;r<8;r++) wcqT[(size_t)tid*256 + i0 + r] = (_Float16)acc[r];
}

// ---------------- bcq = bc @ Wq + bq ----------------
__global__ __launch_bounds__(512) void k_bcq(const float* __restrict__ bc,
                                             const float* __restrict__ Wq,
                                             const float* __restrict__ bq,
                                             float* __restrict__ bcq){
    int j = threadIdx.x;
    float a = bq[j];
    for (int m=0;m<512;m++) a += bc[m]*Wq[(size_t)m*512+j];
    bcq[j] = a;
}

// ---------------- GEMM v3: 128x128 tile, 512 thr, dbuf LDS + reg prefetch ----
// 1 barrier per K-step. grid (N/128, M/128). Wave grid 2x4; wave tile 64x32.
template<typename AT, typename CT, bool QB>
__global__ __launch_bounds__(512) void k_gemm(const AT* __restrict__ A,
                                              const _Float16* __restrict__ WT,
                                              const float* __restrict__ bias,
                                              CT* __restrict__ C,
                                              int M, int N, int K,
                                              float scale,
                                              _Float16* __restrict__ qbT){
    __shared__ _Float16 Al[2][128*64];
    __shared__ _Float16 Wl[2][128*64];
    int tid = threadIdx.x, l = tid&63, w = tid>>6;
    int l15 = l&15, lq = l>>4;
    int wr = w>>2, wc = w&3;
    int m0 = blockIdx.y*128, n0 = blockIdx.x*128;
    v4f acc[4][2] = {};
    float bv[2];
    #pragma unroll
    for (int bc=0;bc<2;++bc) bv[bc] = bias[n0 + wc*32 + bc*16 + l15];
    int srow = tid>>2, sseg = (tid&3)*16;
    const AT* arow = A + (size_t)(m0+srow)*K + sseg;
    const _Float16* wrow = WT + (size_t)(n0+srow)*K + sseg;
    int NT = K>>6;

    v8h pa0, pa1, pw0, pw1;
    if constexpr (sizeof(AT)==4){
        const float* s = (const float*)arow;
        pa0 = cvt8(*(const float4*)s,     *(const float4*)(s+4));
        pa1 = cvt8(*(const float4*)(s+8), *(const float4*)(s+12));
    } else {
        pa0 = *(const v8h*)arow; pa1 = *(const v8h*)(arow+8);
    }
    pw0 = *(const v8h*)wrow; pw1 = *(const v8h*)(wrow+8);
    st8(&Al[0][swz(srow,sseg)], pa0); st8(&Al[0][swz(srow,sseg+8)], pa1);
    st8(&Wl[0][swz(srow,sseg)], pw0); st8(&Wl[0][swz(srow,sseg+8)], pw1);
    __syncthreads();

    for (int kt=0; kt<NT; ++kt){
        int cur = kt&1;
        if (kt < NT-1){
            int k0 = (kt+1)<<6;
            if constexpr (sizeof(AT)==4){
                const float* s = (const float*)arow + k0;
                pa0 = cvt8(*(const float4*)s,     *(const float4*)(s+4));
                pa1 = cvt8(*(const float4*)(s+8), *(const float4*)(s+12));
            } else {
                pa0 = *(const v8h*)(arow + k0); pa1 = *(const v8h*)(arow + k0 + 8);
            }
            pw0 = *(const v8h*)(wrow + k0); pw1 = *(const v8h*)(wrow + k0 + 8);
        }
        #pragma unroll
        for (int kk=0; kk<2; ++kk){
            v8h af[4], bf[2];
            #pragma unroll
            for (int ar=0;ar<4;++ar) af[ar] = *(v8h*)&Al[cur][swz(wr*64+ar*16+l15, kk*32+lq*8)];
            #pragma unroll
            for (int bc=0;bc<2;++bc) bf[bc] = *(v8h*)&Wl[cur][swz(wc*32+bc*16+l15, kk*32+lq*8)];
            #pragma unroll
            for (int ar=0;ar<4;++ar)
                #pragma unroll
                for (int bc=0;bc<2;++bc)
                    acc[ar][bc] = MFMA32(af[ar], bf[bc], acc[ar][bc]);
        }
        if (kt < NT-1){
            st8(&Al[cur^1][swz(srow,sseg)], pa0); st8(&Al[cur^1][swz(srow,sseg+8)], pa1);
            st8(&Wl[cur^1][swz(srow,sseg)], pw0); st8(&Wl[cur^1][swz(srow,sseg+8)], pw1);
        }
        __syncthreads();
    }
    #pragma unroll
    for (int ar=0;ar<4;++ar){
        #pragma unroll
        for (int bc=0;bc<2;++bc){
            #pragma unroll
            for (int i=0;i<4;++i){
                int row = m0 + wr*64 + ar*16 + lq*4 + i;
                int col = n0 + wc*32 + bc*16 + l15;
                float vf = (acc[ar][bc][i] + bv[bc])*scale;
                C[(size_t)row*N + col] = (CT)vf;
                if constexpr (QB){
                    int bI = row>>10, t = row&1023;
                    qbT[((size_t)t<<12) + (bI<<9) + col] = (_Float16)vf;
                }
            }
        }
    }
}

// ---------------- fused K+V projection v3: same structure, two W streams -----
__global__ __launch_bounds__(512) void k_gemmkv(const _Float16* __restrict__ A,
                                                const _Float16* __restrict__ WTk,
                                                const _Float16* __restrict__ WTv,
                                                const float* __restrict__ bk,
                                                const float* __restrict__ bv,
                                                _Float16* __restrict__ Ck,
                                                _Float16* __restrict__ Cv){
    __shared__ _Float16 Al[2][128*64];
    __shared__ _Float16 Wkl[2][128*64];
    __shared__ _Float16 Wvl[2][128*64];
    int tid = threadIdx.x, l = tid&63, w = tid>>6;
    int l15 = l&15, lq = l>>4;
    int wr = w>>2, wc = w&3;
    int m0 = blockIdx.y*128, n0 = blockIdx.x*128;
    v4f ack[4][2] = {}, acv[4][2] = {};
    float bkr[2], bvr[2];
    #pragma unroll
    for (int bc=0;bc<2;++bc){ bkr[bc] = bk[n0 + wc*32 + bc*16 + l15]; bvr[bc] = bv[n0 + wc*32 + bc*16 + l15]; }
    int srow = tid>>2, sseg = (tid&3)*16;
    const _Float16* arow = A   + (size_t)(m0+srow)*512 + sseg;
    const _Float16* krow = WTk + (size_t)(n0+srow)*512 + sseg;
    const _Float16* vrow = WTv + (size_t)(n0+srow)*512 + sseg;

    v8h pa0,pa1,pk0,pk1,pv0,pv1;
    pa0 = *(const v8h*)arow; pa1 = *(const v8h*)(arow+8);
    pk0 = *(const v8h*)krow; pk1 = *(const v8h*)(krow+8);
    pv0 = *(const v8h*)vrow; pv1 = *(const v8h*)(vrow+8);
    st8(&Al[0][swz(srow,sseg)],  pa0); st8(&Al[0][swz(srow,sseg+8)],  pa1);
    st8(&Wkl[0][swz(srow,sseg)], pk0); st8(&Wkl[0][swz(srow,sseg+8)], pk1);
    st8(&Wvl[0][swz(srow,sseg)], pv0); st8(&Wvl[0][swz(srow,sseg+8)], pv1);
    __syncthreads();

    for (int kt=0; kt<8; ++kt){
        int cur = kt&1;
        if (kt < 7){
            int k0 = (kt+1)<<6;
            pa0 = *(const v8h*)(arow+k0); pa1 = *(const v8h*)(arow+k0+8);
            pk0 = *(const v8h*)(krow+k0); pk1 = *(const v8h*)(krow+k0+8);
            pv0 = *(const v8h*)(vrow+k0); pv1 = *(const v8h*)(vrow+k0+8);
        }
        #pragma unroll
        for (int kk=0; kk<2; ++kk){
            v8h af[4], kf[2], vf[2];
            #pragma unroll
            for (int ar=0;ar<4;++ar) af[ar] = *(v8h*)&Al[cur][swz(wr*64+ar*16+l15, kk*32+lq*8)];
            #pragma unroll
            for (int bc=0;bc<2;++bc){
                kf[bc] = *(v8h*)&Wkl[cur][swz(wc*32+bc*16+l15, kk*32+lq*8)];
                vf[bc] = *(v8h*)&Wvl[cur][swz(wc*32+bc*16+l15, kk*32+lq*8)];
            }
            #pragma unroll
            for (int ar=0;ar<4;++ar)
                #pragma unroll
                for (int bc=0;bc<2;++bc){
                    ack[ar][bc] = MFMA32(af[ar], kf[bc], ack[ar][bc]);
                    acv[ar][bc] = MFMA32(af[ar], vf[bc], acv[ar][bc]);
                }
        }
        if (kt < 7){
            st8(&Al[cur^1][swz(srow,sseg)],  pa0); st8(&Al[cur^1][swz(srow,sseg+8)],  pa1);
            st8(&Wkl[cur^1][swz(srow,sseg)], pk0); st8(&Wkl[cur^1][swz(srow,sseg+8)], pk1);
            st8(&Wvl[cur^1][swz(srow,sseg)], pv0); st8(&Wvl[cur^1][swz(srow,sseg+8)], pv1);
        }
        __syncthreads();
    }
    #pragma unroll
    for (int ar=0;ar<4;++ar){
        #pragma unroll
        for (int bc=0;bc<2;++bc){
            #pragma unroll
            for (int i=0;i<4;++i){
                int row = m0 + wr*64 + ar*16 + lq*4 + i;
                int col = n0 + wc*32 + bc*16 + l15;
                Ck[(size_t)row*512 + col] = (_Float16)(ack[ar][bc][i] + bkr[bc]);
                Cv[(size_t)row*512 + col] = (_Float16)(acv[ar][bc][i] + bvr[bc]);
            }
        }
    }
}

// ---------------- bias v7: LDS double-buffer, 1 barrier per chunk ------------
// Sb[t][bh][s] = qb[t,bh,:]·posk[t,s,:], mask folded in the stream-out pass.
// grid 2048 (t = blk>>1, s-half = blk&1), 256 thr (4 waves).
__global__ __launch_bounds__(256) void k_bias(const _Float16* __restrict__ qb,
                                              const float* __restrict__ posk,
                                              const int* __restrict__ mask,
                                              _Float16* __restrict__ Sb){
    __shared__ _Float16 Pl[2][64*64];   // posk chunk [s][d] fp16, swizzled
    __shared__ _Float16 Ol[2][64*72];   // out tile [bh][s], pad 72
    int t = blockIdx.x >> 1, sh = blockIdx.x & 1;
    int tid = threadIdx.x, l = tid&63, w = tid>>6;
    int l31 = l&31, hi = l>>5;
    int g = w & 1, sg = w >> 1;      // wave's bh-group / s-subgroup
    v8h aa[4];
    const _Float16* qbt = qb + ((size_t)t<<12);
    #pragma unroll
    for (int k0=0;k0<4;++k0)
        aa[k0] = *(const v8h*)(qbt + (g*32 + l31)*64 + k0*16 + hi*8);

    const float* pkt = posk + ((size_t)t<<16);
    int sbase = sh*512;
    int lrow = (l>>4), lcol = (l&15)*4;      // within-wave load geometry

    v4f pf[4];
    #pragma unroll
    for (int j=0;j<4;++j)
        pf[j] = *(const v4f*)(pkt + (size_t)(sbase + w*16 + j*4 + lrow)*64 + lcol);

    int obh = tid>>2;
    int osl = (tid&3)*16;
    int ob  = obh>>3;
    const int* mbase = mask + (((size_t)(ob*Tt + t))<<10);
    _Float16* sbb = Sb + (((size_t)(t*64 + obh))<<10);

    // write chunk0 to Pl[0]
    #pragma unroll
    for (int j=0;j<4;++j){
        v4h hv; hv[0]=(_Float16)pf[j][0]; hv[1]=(_Float16)pf[j][1];
                hv[2]=(_Float16)pf[j][2]; hv[3]=(_Float16)pf[j][3];
        *(v4h*)&Pl[0][swz(w*16 + j*4 + lrow, lcol)] = hv;
    }
    __syncthreads();

    for (int sc=0; sc<8; ++sc){
        int cur = sc&1;
        int s0 = sbase + sc*64;
        // prefetch next chunk (lands during MFMA below)
        if (sc < 7){
            #pragma unroll
            for (int j=0;j<4;++j)
                pf[j] = *(const v4f*)(pkt + (size_t)(s0 + 64 + w*16 + j*4 + lrow)*64 + lcol);
        }
        int4 mq[4];
        #pragma unroll
        for (int j=0;j<4;++j)
            mq[j] = *(const int4*)(mbase + s0 + osl + j*4);
        // MFMA from Pl[cur] -> Ol[cur]
        v8h bfr[4];
        #pragma unroll
        for (int k0=0;k0<4;++k0)
            bfr[k0] = *(v8h*)&Pl[cur][swz(sg*32 + l31, k0*16 + hi*8)];
        v16f acc = {};
        #pragma unroll
        for (int k0=0;k0<4;++k0) acc = MFMA3216(aa[k0], bfr[k0], acc);
        #pragma unroll
        for (int r=0;r<16;++r){
            int bh = g*32 + (r&3) + 4*hi + 8*(r>>2);
            Ol[cur][bh*72 + sg*32 + l31] = (_Float16)acc[r];
        }
        // write prefetched posk to Pl[cur^1] (reads of Pl[cur^1] finished at sc-1)
        if (sc < 7){
            #pragma unroll
            for (int j=0;j<4;++j){
                v4h hv; hv[0]=(_Float16)pf[j][0]; hv[1]=(_Float16)pf[j][1];
                        hv[2]=(_Float16)pf[j][2]; hv[3]=(_Float16)pf[j][3];
                *(v4h*)&Pl[cur^1][swz(w*16 + j*4 + lrow, lcol)] = hv;
            }
        }
        __syncthreads();
        // stream out Ol[cur] with mask fold: 32 B/thread coalesced
        v8h o0 = *(v8h*)&Ol[cur][obh*72 + osl];
        v8h o1 = *(v8h*)&Ol[cur][obh*72 + osl + 8];
        const _Float16 NEG = (_Float16)(-30000.f);
        int mm[16] = {mq[0].x,mq[0].y,mq[0].z,mq[0].w, mq[1].x,mq[1].y,mq[1].z,mq[1].w,
                      mq[2].x,mq[2].y,mq[2].z,mq[2].w, mq[3].x,mq[3].y,mq[3].z,mq[3].w};
        #pragma unroll
        for (int j=0;j<8;++j){ if(!mm[j]) o0[j]=NEG; if(!mm[8+j]) o1[j]=NEG; }
        *(v8h*)(sbb + s0 + osl)     = o0;
        *(v8h*)(sbb + s0 + osl + 8) = o1;
    }
}

// ---------------- flash v3: swapped QK (lane-local rows) ---------------------
// grid (64 bh, 8 t-tiles of 128), 512 thr. S = mfma(K, Q): col = t, row = s.
__global__ __launch_bounds__(512) void k_flash(const _Float16* __restrict__ qs,
                                               const _Float16* __restrict__ kbuf,
                                               const _Float16* __restrict__ vbuf,
                                               const _Float16* __restrict__ Sb,
                                               _Float16* __restrict__ ao){
    __shared__ _Float16 Kl[64*64];    // [s][d] swizzled
    __shared__ _Float16 Vt[64*64];    // [d][s] swizzled
    __shared__ _Float16 Bl[128*64];   // bias chunk then P, [t][s] swizzled
    int bh = blockIdx.x; int b = bh>>3, h = bh&7;
    int t0 = blockIdx.y*128;
    int tid = threadIdx.x, l = tid&63, w = tid>>6, l15 = l&15, lq = l>>4;

    v8h qa[2];
    #pragma unroll
    for (int u=0;u<2;++u)
        qa[u] = *(const v8h*)(qs + ((size_t)(b*Tt + t0 + w*16 + l15))*NFf + h*DKk + u*32 + lq*8);

    v4f O[4] = {};
    float m_l = -1e30f, l_l = 0.f;

    int kr = tid>>3, kseg = (tid&7)*8;
    int vs = tid&63, vd0 = (tid>>6)*8;
    int br = tid>>2, bhf = (tid&3)*16;
    const _Float16* kbase = kbuf + ((size_t)(b*Tt + kr))*NFf + h*DKk + kseg;
    const _Float16* vbase = vbuf + ((size_t)(b*Tt + vs))*NFf + h*DKk + vd0;
    const _Float16* bbase = Sb + (((size_t)((t0+br)*64 + bh))<<10) + bhf;

    v8h pk = *(const v8h*)kbase;
    v8h pv = *(const v8h*)vbase;
    v8h pb0 = *(const v8h*)bbase;
    v8h pb1 = *((const v8h*)bbase + 1);

    for (int sc=0; sc<16; ++sc){
        st8(&Kl[swz(kr, kseg)], pk);
        #pragma unroll
        for (int j=0;j<8;j++) Vt[swz(vd0+j, vs)] = pv[j];
        st8(&Bl[swz(br, bhf)],   pb0);
        st8(&Bl[swz(br, bhf+8)], pb1);
        __syncthreads();
        if (sc < 15){
            size_t soff = (size_t)(sc+1)*64;
            pk  = *(const v8h*)(kbase + soff*NFf);
            pv  = *(const v8h*)(vbase + soff*NFf);
            pb0 = *(const v8h*)(bbase + soff);
            pb1 = *((const v8h*)(bbase + soff) + 1);
        }

        v4f sv[4];
        #pragma unroll
        for (int nt=0; nt<4; ++nt){
            v8h kb0 = *(v8h*)&Kl[swz(nt*16+l15, lq*8)];
            v8h kb1 = *(v8h*)&Kl[swz(nt*16+l15, 32+lq*8)];
            v4f a = {};
            a = MFMA32(kb0, qa[0], a);
            a = MFMA32(kb1, qa[1], a);
            v4h bl4 = *(v4h*)&Bl[swz(w*16 + l15, nt*16 + lq*4)];
            #pragma unroll
            for (int i=0;i<4;i++) a[i] += (float)bl4[i];
            sv[nt] = a;
        }
        float mx = fmaxf(fmaxf(fmaxf(sv[0][0],sv[0][1]),fmaxf(sv[0][2],sv[0][3])),
                   fmaxf(fmaxf(fmaxf(sv[1][0],sv[1][1]),fmaxf(sv[1][2],sv[1][3])),
                   fmaxf(fmaxf(fmaxf(sv[2][0],sv[2][1]),fmaxf(sv[2][2],sv[2][3])),
                         fmaxf(fmaxf(sv[3][0],sv[3][1]),fmaxf(sv[3][2],sv[3][3])))));
        mx = fmaxf(mx, __shfl_xor(mx,16));
        mx = fmaxf(mx, __shfl_xor(mx,32));
        float mn = fmaxf(m_l, mx);
        if (__any(mn - m_l > 0.f)){
            float rsc = exp2f(m_l - mn);
            m_l = mn; l_l *= rsc;
            float rscB[4];
            #pragma unroll
            for (int i=0;i<4;i++) rscB[i] = __shfl(rsc, lq*4+i);
            #pragma unroll
            for (int nt=0; nt<4; ++nt)
                #pragma unroll
                for (int i=0;i<4;i++) O[nt][i] *= rscB[i];
        }
        float ps = 0.f;
        #pragma unroll
        for (int nt=0; nt<4; ++nt){
            v4h ph;
            #pragma unroll
            for (int i=0;i<4;i++){
                float p = exp2f(sv[nt][i] - m_l);
                ph[i] = (_Float16)p;
                ps += p;
            }
            *(v4h*)&Bl[swz(w*16 + l15, nt*16 + lq*4)] = ph;
        }
        ps += __shfl_xor(ps,16);
        ps += __shfl_xor(ps,32);
        l_l += ps;
        {
            v8h pa0 = *(v8h*)&Bl[swz(w*16+l15, lq*8)];
            v8h pa1 = *(v8h*)&Bl[swz(w*16+l15, 32+lq*8)];
            #pragma unroll
            for (int nt=0; nt<4; ++nt){
                v8h vb0 = *(v8h*)&Vt[swz(nt*16+l15, lq*8)];
                v8h vb1 = *(v8h*)&Vt[swz(nt*16+l15, 32+lq*8)];
                O[nt] = MFMA32(pa0, vb0, O[nt]);
                O[nt] = MFMA32(pa1, vb1, O[nt]);
            }
        }
        __syncthreads();
    }

    float rl = (l_l > 0.f) ? 1.f/l_l : 0.f;
    float rlB[4];
    #pragma unroll
    for (int i=0;i<4;i++) rlB[i] = __shfl(rl, lq*4+i);
    #pragma unroll
    for (int i=0;i<4;i++){
        int row = t0 + w*16 + lq*4 + i;
        #pragma unroll
        for (int nt=0; nt<4; ++nt)
            ao[((size_t)(b*Tt + row))*NFf + h*DKk + nt*16 + l15] = (_Float16)(O[nt][i]*rlB[i]);
    }
}

// ---------------- launch ----------------
extern "C" void kernel_launch(void* const* d_in, const int* in_sizes, int n_in,
                              void* d_out, int out_size, void* d_ws, size_t ws_size,
                              hipStream_t stream) {
    const float* x       = (const float*)d_in[0];
    const float* cond    = (const float*)d_in[1];
    const float* pos_k   = (const float*)d_in[2];
    const int*   mask    = (const int*)  d_in[3];
    const float* ln_g    = (const float*)d_in[4];
    const float* ln_b    = (const float*)d_in[5];
    const float* Wq      = (const float*)d_in[6];
    const float* bq      = (const float*)d_in[7];
    const float* Wk      = (const float*)d_in[8];
    const float* bk      = (const float*)d_in[9];
    const float* Wv      = (const float*)d_in[10];
    const float* bv      = (const float*)d_in[11];
    const float* Wo      = (const float*)d_in[12];
    const float* bo      = (const float*)d_in[13];
    const float* Wc      = (const float*)d_in[14];
    const float* bc      = (const float*)d_in[15];
    float* out = (float*)d_out;

    char* base = (char*)d_ws;
    const size_t OFF_S    = 0;                       // 134217728 B fp16 Sb
    const size_t OFF_XN   = 134217728;
    const size_t OFF_Q    = OFF_XN  + 8388608;
    const size_t OFF_QB   = OFF_Q   + 8388608;
    const size_t OFF_K    = OFF_QB  + 8388608;
    const size_t OFF_V    = OFF_K   + 8388608;
    const size_t OFF_AO   = OFF_V   + 8388608;
    const size_t OFF_WKT  = OFF_AO  + 8388608;       // 524288
    const size_t OFF_WVT  = OFF_WKT + 524288;
    const size_t OFF_WOT  = OFF_WVT + 524288;
    const size_t OFF_WCQT = OFF_WOT + 524288;        // 262144
    const size_t OFF_BCQ  = OFF_WCQT + 262144;

    _Float16* xn    = (_Float16*)(base + OFF_XN);
    _Float16* qbuf  = (_Float16*)(base + OFF_Q);
    _Float16* qb    = (_Float16*)(base + OFF_QB);
    _Float16* kb    = (_Float16*)(base + OFF_K);
    _Float16* vb    = (_Float16*)(base + OFF_V);
    _Float16* ao    = (_Float16*)(base + OFF_AO);
    _Float16* Sb    = (_Float16*)(base + OFF_S);
    _Float16* WkT   = (_Float16*)(base + OFF_WKT);
    _Float16* WvT   = (_Float16*)(base + OFF_WVT);
    _Float16* WoT   = (_Float16*)(base + OFF_WOT);
    _Float16* wcqT  = (_Float16*)(base + OFF_WCQT);
    float*    bcq   = (float*)(base + OFF_BCQ);

    k_ln<<<dim3(Bb*Tt), dim3(256), 0, stream>>>(x, ln_g, ln_b, xn);
    k_wT<<<dim3(8,8), dim3(256), 0, stream>>>(Wk, WkT);
    k_wT<<<dim3(8,8), dim3(256), 0, stream>>>(Wv, WvT);
    k_wT<<<dim3(8,8), dim3(256), 0, stream>>>(Wo, WoT);
    k_wcq<<<dim3(32), dim3(512), 0, stream>>>(Wc, Wq, wcqT);
    k_bcq<<<dim3(1), dim3(512), 0, stream>>>(bc, Wq, bq, bcq);

    // q projection: writes scaled qbuf AND scaled transposed qb
    k_gemm<float,_Float16,true><<<dim3(4,64), dim3(512), 0, stream>>>(cond, wcqT, bcq, qbuf, Bb*Tt, 512, 256, SCQ, qb);
    // fused K+V projection
    k_gemmkv<<<dim3(4,64), dim3(512), 0, stream>>>(xn, WkT, WvT, bk, bv, kb, vb);

    k_bias<<<dim3(2048), dim3(256), 0, stream>>>(qb, pos_k, mask, Sb);
    k_flash<<<dim3(64,8), dim3(512), 0, stream>>>(qbuf, kb, vb, Sb, ao);

    k_gemm<_Float16,float,false><<<dim3(4,64), dim3(512), 0, stream>>>(ao, WoT, bo, out, Bb*Tt, 512, 512, 1.f, nullptr);
}

// Round 14
// 225.052 us; speedup vs baseline: 1.7384x; 1.3789x over previous
//
#include <hip/hip_runtime.h>

// ---------------- problem constants ----------------
#define Bb 8
#define Tt 1024
#define Hh 8
#define DKk 64
#define NFf 512
#define DCc 256

typedef _Float16 v2h __attribute__((ext_vector_type(2)));
typedef _Float16 v4h __attribute__((ext_vector_type(4)));
typedef _Float16 v8h __attribute__((ext_vector_type(8)));
typedef float    v4f __attribute__((ext_vector_type(4)));
typedef float    v16f __attribute__((ext_vector_type(16)));

#define MFMA32(a,b,c) __builtin_amdgcn_mfma_f32_16x16x32_f16((a),(b),(c),0,0,0)
#define MFMA3216(a,b,c) __builtin_amdgcn_mfma_f32_32x32x16_f16((a),(b),(c),0,0,0)

// scale folded into q: 1/sqrt(64) * log2(e)  (scores live in log2 domain)
#define SCQ 0.1803368801111f

__device__ inline void st8(_Float16* dst, v8h x){
    *(v4h*)dst     = __builtin_shufflevector(x,x,0,1,2,3);
    *(v4h*)(dst+4) = __builtin_shufflevector(x,x,4,5,6,7);
}

__device__ inline v8h cvt8(float4 a, float4 b){
    v8h r;
    r[0]=(_Float16)a.x; r[1]=(_Float16)a.y; r[2]=(_Float16)a.z; r[3]=(_Float16)a.w;
    r[4]=(_Float16)b.x; r[5]=(_Float16)b.y; r[6]=(_Float16)b.z; r[7]=(_Float16)b.w;
    return r;
}

// XOR swizzle for [R][64] half LDS tiles; keeps 8-half granularity
__device__ inline int swz(int r, int c){ return (r*64 + c) ^ ((r&7)<<3); }

// ---------------- LayerNorm: x (8192,512) fp32 -> xn fp16 ----------------
__global__ __launch_bounds__(256) void k_ln(const float* __restrict__ x,
                                            const float* __restrict__ g,
                                            const float* __restrict__ be,
                                            _Float16* __restrict__ xn){
    int row = blockIdx.x; int tid = threadIdx.x;
    const float* xr = x + (size_t)row*512;
    float2 v = reinterpret_cast<const float2*>(xr)[tid];
    float s = v.x + v.y, sq = v.x*v.x + v.y*v.y;
    for (int off=32; off; off>>=1){ s += __shfl_down(s, off); sq += __shfl_down(sq, off); }
    __shared__ float ws_[4], wq_[4];
    __shared__ float mu_s, rs_s;
    int wid = tid>>6, lid = tid&63;
    if (lid==0){ ws_[wid]=s; wq_[wid]=sq; }
    __syncthreads();
    if (tid==0){
        float S=0,Q=0;
        for(int i=0;i<4;i++){S+=ws_[i];Q+=wq_[i];}
        float mu = S*(1.f/512.f);
        float var = Q*(1.f/512.f)-mu*mu;
        mu_s=mu; rs_s=rsqrtf(var+1e-5f);
    }
    __syncthreads();
    float mu=mu_s, rs=rs_s;
    float2 gv = reinterpret_cast<const float2*>(g)[tid];
    float2 bv = reinterpret_cast<const float2*>(be)[tid];
    v2h o; o[0] = (_Float16)((v.x-mu)*rs*gv.x + bv.x);
           o[1] = (_Float16)((v.y-mu)*rs*gv.y + bv.y);
    reinterpret_cast<v2h*>(xn + (size_t)row*512)[tid] = o;
}

// ---------------- weight transpose x4: W (512,512) fp32 -> WT (N,K) fp16 -----
__global__ __launch_bounds__(256) void k_wT4(const float* __restrict__ W0,
                                             const float* __restrict__ W1,
                                             const float* __restrict__ W2,
                                             const float* __restrict__ W3,
                                             _Float16* __restrict__ T0,
                                             _Float16* __restrict__ T1,
                                             _Float16* __restrict__ T2,
                                             _Float16* __restrict__ T3){
    const float* W = (blockIdx.z==0)?W0:(blockIdx.z==1)?W1:(blockIdx.z==2)?W2:W3;
    _Float16*  WT = (blockIdx.z==0)?T0:(blockIdx.z==1)?T1:(blockIdx.z==2)?T2:T3;
    __shared__ float tile[64][65];
    int bx = blockIdx.x*64, by = blockIdx.y*64;   // bx: n-base, by: k-base
    int tid = threadIdx.x, c = tid&63;
    for (int r = tid>>6; r<64; r+=4) tile[r][c] = W[(size_t)(by+r)*512 + bx + c];
    __syncthreads();
    for (int n = tid>>6; n<64; n+=4) WT[(size_t)(bx+n)*512 + by + c] = (_Float16)tile[c][n];
}

// ---------------- fp32 -> fp16 copy (Wc 256x512) ----------------
__global__ __launch_bounds__(256) void k_h16(const float* __restrict__ src,
                                             _Float16* __restrict__ dst){
    int i = (blockIdx.x*256 + threadIdx.x)*8;
    float4 a = *(const float4*)(src+i);
    float4 b = *(const float4*)(src+i+4);
    *(v8h*)(dst+i) = cvt8(a,b);
}

// ---------------- bcq partial dots: bcq[j] += sum_{m in block} bc[m]*Wq[m][j]
__global__ __launch_bounds__(512) void k_bcqp(const float* __restrict__ bc,
                                              const float* __restrict__ Wq,
                                              float* __restrict__ bcq){
    int j = threadIdx.x; int m0 = blockIdx.x*16;
    float a = 0.f;
    #pragma unroll
    for (int m=0;m<16;m++) a += bc[m0+m]*Wq[(size_t)(m0+m)*512 + j];
    atomicAdd(&bcq[j], a);
}

// ---------------- GEMM v3: 128x128 tile, 512 thr, dbuf LDS + reg prefetch ----
// 1 barrier per K-step. grid (N/128, M/128). Wave grid 2x4; wave tile 64x32.
template<typename AT, typename CT, bool QB>
__global__ __launch_bounds__(512) void k_gemm(const AT* __restrict__ A,
                                              const _Float16* __restrict__ WT,
                                              const float* __restrict__ bias,
                                              CT* __restrict__ C,
                                              int M, int N, int K,
                                              float scale,
                                              _Float16* __restrict__ qbT){
    __shared__ _Float16 Al[2][128*64];
    __shared__ _Float16 Wl[2][128*64];
    int tid = threadIdx.x, l = tid&63, w = tid>>6;
    int l15 = l&15, lq = l>>4;
    int wr = w>>2, wc = w&3;
    int m0 = blockIdx.y*128, n0 = blockIdx.x*128;
    v4f acc[4][2] = {};
    float bv[2];
    #pragma unroll
    for (int bc=0;bc<2;++bc) bv[bc] = bias[n0 + wc*32 + bc*16 + l15];
    int srow = tid>>2, sseg = (tid&3)*16;
    const AT* arow = A + (size_t)(m0+srow)*K + sseg;
    const _Float16* wrow = WT + (size_t)(n0+srow)*K + sseg;
    int NT = K>>6;

    v8h pa0, pa1, pw0, pw1;
    if constexpr (sizeof(AT)==4){
        const float* s = (const float*)arow;
        pa0 = cvt8(*(const float4*)s,     *(const float4*)(s+4));
        pa1 = cvt8(*(const float4*)(s+8), *(const float4*)(s+12));
    } else {
        pa0 = *(const v8h*)arow; pa1 = *(const v8h*)(arow+8);
    }
    pw0 = *(const v8h*)wrow; pw1 = *(const v8h*)(wrow+8);
    st8(&Al[0][swz(srow,sseg)], pa0); st8(&Al[0][swz(srow,sseg+8)], pa1);
    st8(&Wl[0][swz(srow,sseg)], pw0); st8(&Wl[0][swz(srow,sseg+8)], pw1);
    __syncthreads();

    for (int kt=0; kt<NT; ++kt){
        int cur = kt&1;
        if (kt < NT-1){
            int k0 = (kt+1)<<6;
            if constexpr (sizeof(AT)==4){
                const float* s = (const float*)arow + k0;
                pa0 = cvt8(*(const float4*)s,     *(const float4*)(s+4));
                pa1 = cvt8(*(const float4*)(s+8), *(const float4*)(s+12));
            } else {
                pa0 = *(const v8h*)(arow + k0); pa1 = *(const v8h*)(arow + k0 + 8);
            }
            pw0 = *(const v8h*)(wrow + k0); pw1 = *(const v8h*)(wrow + k0 + 8);
        }
        #pragma unroll
        for (int kk=0; kk<2; ++kk){
            v8h af[4], bf[2];
            #pragma unroll
            for (int ar=0;ar<4;++ar) af[ar] = *(v8h*)&Al[cur][swz(wr*64+ar*16+l15, kk*32+lq*8)];
            #pragma unroll
            for (int bc=0;bc<2;++bc) bf[bc] = *(v8h*)&Wl[cur][swz(wc*32+bc*16+l15, kk*32+lq*8)];
            #pragma unroll
            for (int ar=0;ar<4;++ar)
                #pragma unroll
                for (int bc=0;bc<2;++bc)
                    acc[ar][bc] = MFMA32(af[ar], bf[bc], acc[ar][bc]);
        }
        if (kt < NT-1){
            st8(&Al[cur^1][swz(srow,sseg)], pa0); st8(&Al[cur^1][swz(srow,sseg+8)], pa1);
            st8(&Wl[cur^1][swz(srow,sseg)], pw0); st8(&Wl[cur^1][swz(srow,sseg+8)], pw1);
        }
        __syncthreads();
    }
    #pragma unroll
    for (int ar=0;ar<4;++ar){
        #pragma unroll
        for (int bc=0;bc<2;++bc){
            #pragma unroll
            for (int i=0;i<4;++i){
                int row = m0 + wr*64 + ar*16 + lq*4 + i;
                int col = n0 + wc*32 + bc*16 + l15;
                float vf = (acc[ar][bc][i] + bv[bc])*scale;
                C[(size_t)row*N + col] = (CT)vf;
                if constexpr (QB){
                    int bI = row>>10, t = row&1023;
                    qbT[((size_t)t<<12) + (bI<<9) + col] = (_Float16)vf;
                }
            }
        }
    }
}

// ---------------- fused K+V projection v3: same structure, two W streams -----
__global__ __launch_bounds__(512) void k_gemmkv(const _Float16* __restrict__ A,
                                                const _Float16* __restrict__ WTk,
                                                const _Float16* __restrict__ WTv,
                                                const float* __restrict__ bk,
                                                const float* __restrict__ bv,
                                                _Float16* __restrict__ Ck,
                                                _Float16* __restrict__ Cv){
    __shared__ _Float16 Al[2][128*64];
    __shared__ _Float16 Wkl[2][128*64];
    __shared__ _Float16 Wvl[2][128*64];
    int tid = threadIdx.x, l = tid&63, w = tid>>6;
    int l15 = l&15, lq = l>>4;
    int wr = w>>2, wc = w&3;
    int m0 = blockIdx.y*128, n0 = blockIdx.x*128;
    v4f ack[4][2] = {}, acv[4][2] = {};
    float bkr[2], bvr[2];
    #pragma unroll
    for (int bc=0;bc<2;++bc){ bkr[bc] = bk[n0 + wc*32 + bc*16 + l15]; bvr[bc] = bv[n0 + wc*32 + bc*16 + l15]; }
    int srow = tid>>2, sseg = (tid&3)*16;
    const _Float16* arow = A   + (size_t)(m0+srow)*512 + sseg;
    const _Float16* krow = WTk + (size_t)(n0+srow)*512 + sseg;
    const _Float16* vrow = WTv + (size_t)(n0+srow)*512 + sseg;

    v8h pa0,pa1,pk0,pk1,pv0,pv1;
    pa0 = *(const v8h*)arow; pa1 = *(const v8h*)(arow+8);
    pk0 = *(const v8h*)krow; pk1 = *(const v8h*)(krow+8);
    pv0 = *(const v8h*)vrow; pv1 = *(const v8h*)(vrow+8);
    st8(&Al[0][swz(srow,sseg)],  pa0); st8(&Al[0][swz(srow,sseg+8)],  pa1);
    st8(&Wkl[0][swz(srow,sseg)], pk0); st8(&Wkl[0][swz(srow,sseg+8)], pk1);
    st8(&Wvl[0][swz(srow,sseg)], pv0); st8(&Wvl[0][swz(srow,sseg+8)], pv1);
    __syncthreads();

    for (int kt=0; kt<8; ++kt){
        int cur = kt&1;
        if (kt < 7){
            int k0 = (kt+1)<<6;
            pa0 = *(const v8h*)(arow+k0); pa1 = *(const v8h*)(arow+k0+8);
            pk0 = *(const v8h*)(krow+k0); pk1 = *(const v8h*)(krow+k0+8);
            pv0 = *(const v8h*)(vrow+k0); pv1 = *(const v8h*)(vrow+k0+8);
        }
        #pragma unroll
        for (int kk=0; kk<2; ++kk){
            v8h af[4], kf[2], vf[2];
            #pragma unroll
            for (int ar=0;ar<4;++ar) af[ar] = *(v8h*)&Al[cur][swz(wr*64+ar*16+l15, kk*32+lq*8)];
            #pragma unroll
            for (int bc=0;bc<2;++bc){
                kf[bc] = *(v8h*)&Wkl[cur][swz(wc*32+bc*16+l15, kk*32+lq*8)];
                vf[bc] = *(v8h*)&Wvl[cur][swz(wc*32+bc*16+l15, kk*32+lq*8)];
            }
            #pragma unroll
            for (int ar=0;ar<4;++ar)
                #pragma unroll
                for (int bc=0;bc<2;++bc){
                    ack[ar][bc] = MFMA32(af[ar], kf[bc], ack[ar][bc]);
                    acv[ar][bc] = MFMA32(af[ar], vf[bc], acv[ar][bc]);
                }
        }
        if (kt < 7){
            st8(&Al[cur^1][swz(srow,sseg)],  pa0); st8(&Al[cur^1][swz(srow,sseg+8)],  pa1);
            st8(&Wkl[cur^1][swz(srow,sseg)], pk0); st8(&Wkl[cur^1][swz(srow,sseg+8)], pk1);
            st8(&Wvl[cur^1][swz(srow,sseg)], pv0); st8(&Wvl[cur^1][swz(srow,sseg+8)], pv1);
        }
        __syncthreads();
    }
    #pragma unroll
    for (int ar=0;ar<4;++ar){
        #pragma unroll
        for (int bc=0;bc<2;++bc){
            #pragma unroll
            for (int i=0;i<4;++i){
                int row = m0 + wr*64 + ar*16 + lq*4 + i;
                int col = n0 + wc*32 + bc*16 + l15;
                Ck[(size_t)row*512 + col] = (_Float16)(ack[ar][bc][i] + bkr[bc]);
                Cv[(size_t)row*512 + col] = (_Float16)(acv[ar][bc][i] + bvr[bc]);
            }
        }
    }
}

// ---------------- bias v7: LDS double-buffer, 1 barrier per chunk ------------
__global__ __launch_bounds__(256) void k_bias(const _Float16* __restrict__ qb,
                                              const float* __restrict__ posk,
                                              const int* __restrict__ mask,
                                              _Float16* __restrict__ Sb){
    __shared__ _Float16 Pl[2][64*64];   // posk chunk [s][d] fp16, swizzled
    __shared__ _Float16 Ol[2][64*72];   // out tile [bh][s], pad 72
    int t = blockIdx.x >> 1, sh = blockIdx.x & 1;
    int tid = threadIdx.x, l = tid&63, w = tid>>6;
    int l31 = l&31, hi = l>>5;
    int g = w & 1, sg = w >> 1;      // wave's bh-group / s-subgroup
    v8h aa[4];
    const _Float16* qbt = qb + ((size_t)t<<12);
    #pragma unroll
    for (int k0=0;k0<4;++k0)
        aa[k0] = *(const v8h*)(qbt + (g*32 + l31)*64 + k0*16 + hi*8);

    const float* pkt = posk + ((size_t)t<<16);
    int sbase = sh*512;
    int lrow = (l>>4), lcol = (l&15)*4;      // within-wave load geometry

    v4f pf[4];
    #pragma unroll
    for (int j=0;j<4;++j)
        pf[j] = *(const v4f*)(pkt + (size_t)(sbase + w*16 + j*4 + lrow)*64 + lcol);

    int obh = tid>>2;
    int osl = (tid&3)*16;
    int ob  = obh>>3;
    const int* mbase = mask + (((size_t)(ob*Tt + t))<<10);
    _Float16* sbb = Sb + (((size_t)(t*64 + obh))<<10);

    // write chunk0 to Pl[0]
    #pragma unroll
    for (int j=0;j<4;++j){
        v4h hv; hv[0]=(_Float16)pf[j][0]; hv[1]=(_Float16)pf[j][1];
                hv[2]=(_Float16)pf[j][2]; hv[3]=(_Float16)pf[j][3];
        *(v4h*)&Pl[0][swz(w*16 + j*4 + lrow, lcol)] = hv;
    }
    __syncthreads();

    for (int sc=0; sc<8; ++sc){
        int cur = sc&1;
        int s0 = sbase + sc*64;
        if (sc < 7){
            #pragma unroll
            for (int j=0;j<4;++j)
                pf[j] = *(const v4f*)(pkt + (size_t)(s0 + 64 + w*16 + j*4 + lrow)*64 + lcol);
        }
        int4 mq[4];
        #pragma unroll
        for (int j=0;j<4;++j)
            mq[j] = *(const int4*)(mbase + s0 + osl + j*4);
        v8h bfr[4];
        #pragma unroll
        for (int k0=0;k0<4;++k0)
            bfr[k0] = *(v8h*)&Pl[cur][swz(sg*32 + l31, k0*16 + hi*8)];
        v16f acc = {};
        #pragma unroll
        for (int k0=0;k0<4;++k0) acc = MFMA3216(aa[k0], bfr[k0], acc);
        #pragma unroll
        for (int r=0;r<16;++r){
            int bh = g*32 + (r&3) + 4*hi + 8*(r>>2);
            Ol[cur][bh*72 + sg*32 + l31] = (_Float16)acc[r];
        }
        if (sc < 7){
            #pragma unroll
            for (int j=0;j<4;++j){
                v4h hv; hv[0]=(_Float16)pf[j][0]; hv[1]=(_Float16)pf[j][1];
                        hv[2]=(_Float16)pf[j][2]; hv[3]=(_Float16)pf[j][3];
                *(v4h*)&Pl[cur^1][swz(w*16 + j*4 + lrow, lcol)] = hv;
            }
        }
        __syncthreads();
        v8h o0 = *(v8h*)&Ol[cur][obh*72 + osl];
        v8h o1 = *(v8h*)&Ol[cur][obh*72 + osl + 8];
        const _Float16 NEG = (_Float16)(-30000.f);
        int mm[16] = {mq[0].x,mq[0].y,mq[0].z,mq[0].w, mq[1].x,mq[1].y,mq[1].z,mq[1].w,
                      mq[2].x,mq[2].y,mq[2].z,mq[2].w, mq[3].x,mq[3].y,mq[3].z,mq[3].w};
        #pragma unroll
        for (int j=0;j<8;++j){ if(!mm[j]) o0[j]=NEG; if(!mm[8+j]) o1[j]=NEG; }
        *(v8h*)(sbb + s0 + osl)     = o0;
        *(v8h*)(sbb + s0 + osl + 8) = o1;
    }
}

// ---------------- flash v3: swapped QK (lane-local rows) ---------------------
__global__ __launch_bounds__(512) void k_flash(const _Float16* __restrict__ qs,
                                               const _Float16* __restrict__ kbuf,
                                               const _Float16* __restrict__ vbuf,
                                               const _Float16* __restrict__ Sb,
                                               _Float16* __restrict__ ao){
    __shared__ _Float16 Kl[64*64];    // [s][d] swizzled
    __shared__ _Float16 Vt[64*64];    // [d][s] swizzled
    __shared__ _Float16 Bl[128*64];   // bias chunk then P, [t][s] swizzled
    int bh = blockIdx.x; int b = bh>>3, h = bh&7;
    int t0 = blockIdx.y*128;
    int tid = threadIdx.x, l = tid&63, w = tid>>6, l15 = l&15, lq = l>>4;

    v8h qa[2];
    #pragma unroll
    for (int u=0;u<2;++u)
        qa[u] = *(const v8h*)(qs + ((size_t)(b*Tt + t0 + w*16 + l15))*NFf + h*DKk + u*32 + lq*8);

    v4f O[4] = {};
    float m_l = -1e30f, l_l = 0.f;

    int kr = tid>>3, kseg = (tid&7)*8;
    int vs = tid&63, vd0 = (tid>>6)*8;
    int br = tid>>2, bhf = (tid&3)*16;
    const _Float16* kbase = kbuf + ((size_t)(b*Tt + kr))*NFf + h*DKk + kseg;
    const _Float16* vbase = vbuf + ((size_t)(b*Tt + vs))*NFf + h*DKk + vd0;
    const _Float16* bbase = Sb + (((size_t)((t0+br)*64 + bh))<<10) + bhf;

    v8h pk = *(const v8h*)kbase;
    v8h pv = *(const v8h*)vbase;
    v8h pb0 = *(const v8h*)bbase;
    v8h pb1 = *((const v8h*)bbase + 1);

    for (int sc=0; sc<16; ++sc){
        st8(&Kl[swz(kr, kseg)], pk);
        #pragma unroll
        for (int j=0;j<8;j++) Vt[swz(vd0+j, vs)] = pv[j];
        st8(&Bl[swz(br, bhf)],   pb0);
        st8(&Bl[swz(br, bhf+8)], pb1);
        __syncthreads();
        if (sc < 15){
            size_t soff = (size_t)(sc+1)*64;
            pk  = *(const v8h*)(kbase + soff*NFf);
            pv  = *(const v8h*)(vbase + soff*NFf);
            pb0 = *(const v8h*)(bbase + soff);
            pb1 = *((const v8h*)(bbase + soff) + 1);
        }

        v4f sv[4];
        #pragma unroll
        for (int nt=0; nt<4; ++nt){
            v8h kb0 = *(v8h*)&Kl[swz(nt*16+l15, lq*8)];
            v8h kb1 = *(v8h*)&Kl[swz(nt*16+l15, 32+lq*8)];
            v4f a = {};
            a = MFMA32(kb0, qa[0], a);
            a = MFMA32(kb1, qa[1], a);
            v4h bl4 = *(v4h*)&Bl[swz(w*16 + l15, nt*16 + lq*4)];
            #pragma unroll
            for (int i=0;i<4;i++) a[i] += (float)bl4[i];
            sv[nt] = a;
        }
        float mx = fmaxf(fmaxf(fmaxf(sv[0][0],sv[0][1]),fmaxf(sv[0][2],sv[0][3])),
                   fmaxf(fmaxf(fmaxf(sv[1][0],sv[1][1]),fmaxf(sv[1][2],sv[1][3])),
                   fmaxf(fmaxf(fmaxf(sv[2][0],sv[2][1]),fmaxf(sv[2][2],sv[2][3])),
                         fmaxf(fmaxf(sv[3][0],sv[3][1]),fmaxf(sv[3][2],sv[3][3])))));
        mx = fmaxf(mx, __shfl_xor(mx,16));
        mx = fmaxf(mx, __shfl_xor(mx,32));
        float mn = fmaxf(m_l, mx);
        if (__any(mn - m_l > 0.f)){
            float rsc = exp2f(m_l - mn);
            m_l = mn; l_l *= rsc;
            float rscB[4];
            #pragma unroll
            for (int i=0;i<4;i++) rscB[i] = __shfl(rsc, lq*4+i);
            #pragma unroll
            for (int nt=0; nt<4; ++nt)
                #pragma unroll
                for (int i=0;i<4;i++) O[nt][i] *= rscB[i];
        }
        float ps = 0.f;
        #pragma unroll
        for (int nt=0; nt<4; ++nt){
            v4h ph;
            #pragma unroll
            for (int i=0;i<4;i++){
                float p = exp2f(sv[nt][i] - m_l);
                ph[i] = (_Float16)p;
                ps += p;
            }
            *(v4h*)&Bl[swz(w*16 + l15, nt*16 + lq*4)] = ph;
        }
        ps += __shfl_xor(ps,16);
        ps += __shfl_xor(ps,32);
        l_l += ps;
        {
            v8h pa0 = *(v8h*)&Bl[swz(w*16+l15, lq*8)];
            v8h pa1 = *(v8h*)&Bl[swz(w*16+l15, 32+lq*8)];
            #pragma unroll
            for (int nt=0; nt<4; ++nt){
                v8h vb0 = *(v8h*)&Vt[swz(nt*16+l15, lq*8)];
                v8h vb1 = *(v8h*)&Vt[swz(nt*16+l15, 32+lq*8)];
                O[nt] = MFMA32(pa0, vb0, O[nt]);
                O[nt] = MFMA32(pa1, vb1, O[nt]);
            }
        }
        __syncthreads();
    }

    float rl = (l_l > 0.f) ? 1.f/l_l : 0.f;
    float rlB[4];
    #pragma unroll
    for (int i=0;i<4;i++) rlB[i] = __shfl(rl, lq*4+i);
    #pragma unroll
    for (int i=0;i<4;i++){
        int row = t0 + w*16 + lq*4 + i;
        #pragma unroll
        for (int nt=0; nt<4; ++nt)
            ao[((size_t)(b*Tt + row))*NFf + h*DKk + nt*16 + l15] = (_Float16)(O[nt][i]*rlB[i]);
    }
}

// ---------------- launch ----------------
extern "C" void kernel_launch(void* const* d_in, const int* in_sizes, int n_in,
                              void* d_out, int out_size, void* d_ws, size_t ws_size,
                              hipStream_t stream) {
    const float* x       = (const float*)d_in[0];
    const float* cond    = (const float*)d_in[1];
    const float* pos_k   = (const float*)d_in[2];
    const int*   mask    = (const int*)  d_in[3];
    const float* ln_g    = (const float*)d_in[4];
    const float* ln_b    = (const float*)d_in[5];
    const float* Wq      = (const float*)d_in[6];
    const float* bq      = (const float*)d_in[7];
    const float* Wk      = (const float*)d_in[8];
    const float* bk      = (const float*)d_in[9];
    const float* Wv      = (const float*)d_in[10];
    const float* bv      = (const float*)d_in[11];
    const float* Wo      = (const float*)d_in[12];
    const float* bo      = (const float*)d_in[13];
    const float* Wc      = (const float*)d_in[14];
    const float* bc      = (const float*)d_in[15];
    float* out = (float*)d_out;

    char* base = (char*)d_ws;
    const size_t OFF_S    = 0;                       // 134217728 B fp16 Sb
    const size_t OFF_XN   = 134217728;
    const size_t OFF_Q    = OFF_XN  + 8388608;
    const size_t OFF_QB   = OFF_Q   + 8388608;
    const size_t OFF_K    = OFF_QB  + 8388608;
    const size_t OFF_V    = OFF_K   + 8388608;
    const size_t OFF_AO   = OFF_V   + 8388608;
    const size_t OFF_WKT  = OFF_AO  + 8388608;       // 524288
    const size_t OFF_WVT  = OFF_WKT + 524288;
    const size_t OFF_WOT  = OFF_WVT + 524288;
    const size_t OFF_WQT  = OFF_WOT + 524288;        // 524288
    const size_t OFF_WCH  = OFF_WQT + 524288;        // 262144
    const size_t OFF_WCQT = OFF_WCH + 262144;        // 262144
    const size_t OFF_BCQ  = OFF_WCQT + 262144;       // 2048
    const size_t OFF_ZERO = OFF_BCQ + 2048;          // 1024

    _Float16* xn    = (_Float16*)(base + OFF_XN);
    _Float16* qbuf  = (_Float16*)(base + OFF_Q);
    _Float16* qb    = (_Float16*)(base + OFF_QB);
    _Float16* kb    = (_Float16*)(base + OFF_K);
    _Float16* vb    = (_Float16*)(base + OFF_V);
    _Float16* ao    = (_Float16*)(base + OFF_AO);
    _Float16* Sb    = (_Float16*)(base + OFF_S);
    _Float16* WkT   = (_Float16*)(base + OFF_WKT);
    _Float16* WvT   = (_Float16*)(base + OFF_WVT);
    _Float16* WoT   = (_Float16*)(base + OFF_WOT);
    _Float16* WqT   = (_Float16*)(base + OFF_WQT);
    _Float16* WcH   = (_Float16*)(base + OFF_WCH);
    _Float16* wcqT  = (_Float16*)(base + OFF_WCQT);
    float*    bcq   = (float*)(base + OFF_BCQ);
    float*    zero  = (float*)(base + OFF_ZERO);

    // prep: zero bias, bcq = bq (then accumulate partial dots)
    hipMemsetAsync(zero, 0, 1024, stream);
    hipMemcpyAsync(bcq, bq, 2048, hipMemcpyDeviceToDevice, stream);

    k_ln<<<dim3(Bb*Tt), dim3(256), 0, stream>>>(x, ln_g, ln_b, xn);
    k_wT4<<<dim3(8,8,4), dim3(256), 0, stream>>>(Wk, Wv, Wo, Wq, WkT, WvT, WoT, WqT);
    k_h16<<<dim3(64), dim3(256), 0, stream>>>(Wc, WcH);
    k_bcqp<<<dim3(16), dim3(512), 0, stream>>>(bc, Wq, bcq);

    // wcqT(512x256) = WqT(512x512) @ WcH(256x512)^T  via GEMM v3
    k_gemm<_Float16,_Float16,false><<<dim3(2,4), dim3(512), 0, stream>>>(WqT, WcH, zero, wcqT, 512, 256, 512, 1.f, nullptr);

    // q projection: writes scaled qbuf AND scaled transposed qb
    k_gemm<float,_Float16,true><<<dim3(4,64), dim3(512), 0, stream>>>(cond, wcqT, bcq, qbuf, Bb*Tt, 512, 256, SCQ, qb);
    // fused K+V projection
    k_gemmkv<<<dim3(4,64), dim3(512), 0, stream>>>(xn, WkT, WvT, bk, bv, kb, vb);

    k_bias<<<dim3(2048), dim3(256), 0, stream>>>(qb, pos_k, mask, Sb);
    k_flash<<<dim3(64,8), dim3(512), 0, stream>>>(qbuf, kb, vb, Sb, ao);

    k_gemm<_Float16,float,false><<<dim3(4,64), dim3(512), 0, stream>>>(ao, WoT, bo, out, Bb*Tt, 512, 512, 1.f, nullptr);
}

// Round 15
// 217.158 us; speedup vs baseline: 1.8016x; 1.0364x over previous
//
#include <hip/hip_runtime.h>

// ---------------- problem constants ----------------
#define Bb 8
#define Tt 1024
#define Hh 8
#define DKk 64
#define NFf 512
#define DCc 256

typedef _Float16 v2h __attribute__((ext_vector_type(2)));
typedef _Float16 v4h __attribute__((ext_vector_type(4)));
typedef _Float16 v8h __attribute__((ext_vector_type(8)));
typedef float    v4f __attribute__((ext_vector_type(4)));
typedef float    v16f __attribute__((ext_vector_type(16)));

#define MFMA32(a,b,c) __builtin_amdgcn_mfma_f32_16x16x32_f16((a),(b),(c),0,0,0)
#define MFMA3216(a,b,c) __builtin_amdgcn_mfma_f32_32x32x16_f16((a),(b),(c),0,0,0)

// scale folded into q: 1/sqrt(64) * log2(e)  (scores live in log2 domain)
#define SCQ 0.1803368801111f

__device__ inline void st8(_Float16* dst, v8h x){
    *(v4h*)dst     = __builtin_shufflevector(x,x,0,1,2,3);
    *(v4h*)(dst+4) = __builtin_shufflevector(x,x,4,5,6,7);
}

__device__ inline v8h cvt8(float4 a, float4 b){
    v8h r;
    r[0]=(_Float16)a.x; r[1]=(_Float16)a.y; r[2]=(_Float16)a.z; r[3]=(_Float16)a.w;
    r[4]=(_Float16)b.x; r[5]=(_Float16)b.y; r[6]=(_Float16)b.z; r[7]=(_Float16)b.w;
    return r;
}

// XOR swizzle for [R][64] half LDS tiles; keeps 8-half granularity
__device__ inline int swz(int r, int c){ return (r*64 + c) ^ ((r&7)<<3); }

// ---------------- LayerNorm: x (8192,512) fp32 -> xn fp16 ----------------
__global__ __launch_bounds__(256) void k_ln(const float* __restrict__ x,
                                            const float* __restrict__ g,
                                            const float* __restrict__ be,
                                            _Float16* __restrict__ xn){
    int row = blockIdx.x; int tid = threadIdx.x;
    const float* xr = x + (size_t)row*512;
    float2 v = reinterpret_cast<const float2*>(xr)[tid];
    float s = v.x + v.y, sq = v.x*v.x + v.y*v.y;
    for (int off=32; off; off>>=1){ s += __shfl_down(s, off); sq += __shfl_down(sq, off); }
    __shared__ float ws_[4], wq_[4];
    __shared__ float mu_s, rs_s;
    int wid = tid>>6, lid = tid&63;
    if (lid==0){ ws_[wid]=s; wq_[wid]=sq; }
    __syncthreads();
    if (tid==0){
        float S=0,Q=0;
        for(int i=0;i<4;i++){S+=ws_[i];Q+=wq_[i];}
        float mu = S*(1.f/512.f);
        float var = Q*(1.f/512.f)-mu*mu;
        mu_s=mu; rs_s=rsqrtf(var+1e-5f);
    }
    __syncthreads();
    float mu=mu_s, rs=rs_s;
    float2 gv = reinterpret_cast<const float2*>(g)[tid];
    float2 bv = reinterpret_cast<const float2*>(be)[tid];
    v2h o; o[0] = (_Float16)((v.x-mu)*rs*gv.x + bv.x);
           o[1] = (_Float16)((v.y-mu)*rs*gv.y + bv.y);
    reinterpret_cast<v2h*>(xn + (size_t)row*512)[tid] = o;
}

// ---------------- prep: 4x weight transpose + Wc->fp16 + zero + bcq init -----
__global__ __launch_bounds__(256) void k_prep(const float* __restrict__ Wk,
                                              const float* __restrict__ Wv,
                                              const float* __restrict__ Wo,
                                              const float* __restrict__ Wq,
                                              _Float16* __restrict__ WkT,
                                              _Float16* __restrict__ WvT,
                                              _Float16* __restrict__ WoT,
                                              _Float16* __restrict__ WqT,
                                              const float* __restrict__ Wc,
                                              _Float16* __restrict__ WcH,
                                              const float* __restrict__ bq,
                                              float* __restrict__ bcq,
                                              float* __restrict__ zero){
    __shared__ float tile[64][65];
    int z = blockIdx.z;
    int tid = threadIdx.x;
    if (z < 4){
        const float* W = (z==0)?Wk:(z==1)?Wv:(z==2)?Wo:Wq;
        _Float16*  WT = (z==0)?WkT:(z==1)?WvT:(z==2)?WoT:WqT;
        int bx = blockIdx.x*64, by = blockIdx.y*64;
        int c = tid&63;
        for (int r = tid>>6; r<64; r+=4) tile[r][c] = W[(size_t)(by+r)*512 + bx + c];
        __syncthreads();
        for (int n = tid>>6; n<64; n+=4) WT[(size_t)(bx+n)*512 + by + c] = (_Float16)tile[c][n];
    } else {
        int idx = blockIdx.y*8 + blockIdx.x;   // 0..63
        int i = (idx*256 + tid)*8;
        float4 a = *(const float4*)(Wc+i);
        float4 b2 = *(const float4*)(Wc+i+4);
        *(v8h*)(WcH+i) = cvt8(a,b2);
        if (idx == 0) zero[tid] = 0.f;
        if (idx == 1){ bcq[tid] = bq[tid]; bcq[tid+256] = bq[tid+256]; }
    }
}

// ---------------- bcq partial dots: bcq[j] += sum_{m in block} bc[m]*Wq[m][j]
__global__ __launch_bounds__(512) void k_bcqp(const float* __restrict__ bc,
                                              const float* __restrict__ Wq,
                                              float* __restrict__ bcq){
    int j = threadIdx.x; int m0 = blockIdx.x*16;
    float a = 0.f;
    #pragma unroll
    for (int m=0;m<16;m++) a += bc[m0+m]*Wq[(size_t)(m0+m)*512 + j];
    atomicAdd(&bcq[j], a);
}

// ---------------- GEMM v3: 128x128 tile, 512 thr, dbuf LDS + reg prefetch ----
template<typename AT, typename CT, bool QB>
__global__ __launch_bounds__(512) void k_gemm(const AT* __restrict__ A,
                                              const _Float16* __restrict__ WT,
                                              const float* __restrict__ bias,
                                              CT* __restrict__ C,
                                              int M, int N, int K,
                                              float scale,
                                              _Float16* __restrict__ qbT){
    __shared__ _Float16 Al[2][128*64];
    __shared__ _Float16 Wl[2][128*64];
    int tid = threadIdx.x, l = tid&63, w = tid>>6;
    int l15 = l&15, lq = l>>4;
    int wr = w>>2, wc = w&3;
    int m0 = blockIdx.y*128, n0 = blockIdx.x*128;
    v4f acc[4][2] = {};
    float bv[2];
    #pragma unroll
    for (int bc=0;bc<2;++bc) bv[bc] = bias[n0 + wc*32 + bc*16 + l15];
    int srow = tid>>2, sseg = (tid&3)*16;
    const AT* arow = A + (size_t)(m0+srow)*K + sseg;
    const _Float16* wrow = WT + (size_t)(n0+srow)*K + sseg;
    int NT = K>>6;

    v8h pa0, pa1, pw0, pw1;
    if constexpr (sizeof(AT)==4){
        const float* s = (const float*)arow;
        pa0 = cvt8(*(const float4*)s,     *(const float4*)(s+4));
        pa1 = cvt8(*(const float4*)(s+8), *(const float4*)(s+12));
    } else {
        pa0 = *(const v8h*)arow; pa1 = *(const v8h*)(arow+8);
    }
    pw0 = *(const v8h*)wrow; pw1 = *(const v8h*)(wrow+8);
    st8(&Al[0][swz(srow,sseg)], pa0); st8(&Al[0][swz(srow,sseg+8)], pa1);
    st8(&Wl[0][swz(srow,sseg)], pw0); st8(&Wl[0][swz(srow,sseg+8)], pw1);
    __syncthreads();

    for (int kt=0; kt<NT; ++kt){
        int cur = kt&1;
        if (kt < NT-1){
            int k0 = (kt+1)<<6;
            if constexpr (sizeof(AT)==4){
                const float* s = (const float*)arow + k0;
                pa0 = cvt8(*(const float4*)s,     *(const float4*)(s+4));
                pa1 = cvt8(*(const float4*)(s+8), *(const float4*)(s+12));
            } else {
                pa0 = *(const v8h*)(arow + k0); pa1 = *(const v8h*)(arow + k0 + 8);
            }
            pw0 = *(const v8h*)(wrow + k0); pw1 = *(const v8h*)(wrow + k0 + 8);
        }
        #pragma unroll
        for (int kk=0; kk<2; ++kk){
            v8h af[4], bf[2];
            #pragma unroll
            for (int ar=0;ar<4;++ar) af[ar] = *(v8h*)&Al[cur][swz(wr*64+ar*16+l15, kk*32+lq*8)];
            #pragma unroll
            for (int bc=0;bc<2;++bc) bf[bc] = *(v8h*)&Wl[cur][swz(wc*32+bc*16+l15, kk*32+lq*8)];
            #pragma unroll
            for (int ar=0;ar<4;++ar)
                #pragma unroll
                for (int bc=0;bc<2;++bc)
                    acc[ar][bc] = MFMA32(af[ar], bf[bc], acc[ar][bc]);
        }
        if (kt < NT-1){
            st8(&Al[cur^1][swz(srow,sseg)], pa0); st8(&Al[cur^1][swz(srow,sseg+8)], pa1);
            st8(&Wl[cur^1][swz(srow,sseg)], pw0); st8(&Wl[cur^1][swz(srow,sseg+8)], pw1);
        }
        __syncthreads();
    }
    #pragma unroll
    for (int ar=0;ar<4;++ar){
        #pragma unroll
        for (int bc=0;bc<2;++bc){
            #pragma unroll
            for (int i=0;i<4;++i){
                int row = m0 + wr*64 + ar*16 + lq*4 + i;
                int col = n0 + wc*32 + bc*16 + l15;
                float vf = (acc[ar][bc][i] + bv[bc])*scale;
                C[(size_t)row*N + col] = (CT)vf;
                if constexpr (QB){
                    int bI = row>>10, t = row&1023;
                    qbT[((size_t)t<<12) + (bI<<9) + col] = (_Float16)vf;
                }
            }
        }
    }
}

// ---------------- fused K+V projection v3: same structure, two W streams -----
__global__ __launch_bounds__(512) void k_gemmkv(const _Float16* __restrict__ A,
                                                const _Float16* __restrict__ WTk,
                                                const _Float16* __restrict__ WTv,
                                                const float* __restrict__ bk,
                                                const float* __restrict__ bv,
                                                _Float16* __restrict__ Ck,
                                                _Float16* __restrict__ Cv){
    __shared__ _Float16 Al[2][128*64];
    __shared__ _Float16 Wkl[2][128*64];
    __shared__ _Float16 Wvl[2][128*64];
    int tid = threadIdx.x, l = tid&63, w = tid>>6;
    int l15 = l&15, lq = l>>4;
    int wr = w>>2, wc = w&3;
    int m0 = blockIdx.y*128, n0 = blockIdx.x*128;
    v4f ack[4][2] = {}, acv[4][2] = {};
    float bkr[2], bvr[2];
    #pragma unroll
    for (int bc=0;bc<2;++bc){ bkr[bc] = bk[n0 + wc*32 + bc*16 + l15]; bvr[bc] = bv[n0 + wc*32 + bc*16 + l15]; }
    int srow = tid>>2, sseg = (tid&3)*16;
    const _Float16* arow = A   + (size_t)(m0+srow)*512 + sseg;
    const _Float16* krow = WTk + (size_t)(n0+srow)*512 + sseg;
    const _Float16* vrow = WTv + (size_t)(n0+srow)*512 + sseg;

    v8h pa0,pa1,pk0,pk1,pv0,pv1;
    pa0 = *(const v8h*)arow; pa1 = *(const v8h*)(arow+8);
    pk0 = *(const v8h*)krow; pk1 = *(const v8h*)(krow+8);
    pv0 = *(const v8h*)vrow; pv1 = *(const v8h*)(vrow+8);
    st8(&Al[0][swz(srow,sseg)],  pa0); st8(&Al[0][swz(srow,sseg+8)],  pa1);
    st8(&Wkl[0][swz(srow,sseg)], pk0); st8(&Wkl[0][swz(srow,sseg+8)], pk1);
    st8(&Wvl[0][swz(srow,sseg)], pv0); st8(&Wvl[0][swz(srow,sseg+8)], pv1);
    __syncthreads();

    for (int kt=0; kt<8; ++kt){
        int cur = kt&1;
        if (kt < 7){
            int k0 = (kt+1)<<6;
            pa0 = *(const v8h*)(arow+k0); pa1 = *(const v8h*)(arow+k0+8);
            pk0 = *(const v8h*)(krow+k0); pk1 = *(const v8h*)(krow+k0+8);
            pv0 = *(const v8h*)(vrow+k0); pv1 = *(const v8h*)(vrow+k0+8);
        }
        #pragma unroll
        for (int kk=0; kk<2; ++kk){
            v8h af[4], kf[2], vf[2];
            #pragma unroll
            for (int ar=0;ar<4;++ar) af[ar] = *(v8h*)&Al[cur][swz(wr*64+ar*16+l15, kk*32+lq*8)];
            #pragma unroll
            for (int bc=0;bc<2;++bc){
                kf[bc] = *(v8h*)&Wkl[cur][swz(wc*32+bc*16+l15, kk*32+lq*8)];
                vf[bc] = *(v8h*)&Wvl[cur][swz(wc*32+bc*16+l15, kk*32+lq*8)];
            }
            #pragma unroll
            for (int ar=0;ar<4;++ar)
                #pragma unroll
                for (int bc=0;bc<2;++bc){
                    ack[ar][bc] = MFMA32(af[ar], kf[bc], ack[ar][bc]);
                    acv[ar][bc] = MFMA32(af[ar], vf[bc], acv[ar][bc]);
                }
        }
        if (kt < 7){
            st8(&Al[cur^1][swz(srow,sseg)],  pa0); st8(&Al[cur^1][swz(srow,sseg+8)],  pa1);
            st8(&Wkl[cur^1][swz(srow,sseg)], pk0); st8(&Wkl[cur^1][swz(srow,sseg+8)], pk1);
            st8(&Wvl[cur^1][swz(srow,sseg)], pv0); st8(&Wvl[cur^1][swz(srow,sseg+8)], pv1);
        }
        __syncthreads();
    }
    #pragma unroll
    for (int ar=0;ar<4;++ar){
        #pragma unroll
        for (int bc=0;bc<2;++bc){
            #pragma unroll
            for (int i=0;i<4;++i){
                int row = m0 + wr*64 + ar*16 + lq*4 + i;
                int col = n0 + wc*32 + bc*16 + l15;
                Ck[(size_t)row*512 + col] = (_Float16)(ack[ar][bc][i] + bkr[bc]);
                Cv[(size_t)row*512 + col] = (_Float16)(acv[ar][bc][i] + bvr[bc]);
            }
        }
    }
}

// ---------------- bias v7: LDS double-buffer, 1 barrier per chunk ------------
__global__ __launch_bounds__(256) void k_bias(const _Float16* __restrict__ qb,
                                              const float* __restrict__ posk,
                                              const int* __restrict__ mask,
                                              _Float16* __restrict__ Sb){
    __shared__ _Float16 Pl[2][64*64];   // posk chunk [s][d] fp16, swizzled
    __shared__ _Float16 Ol[2][64*72];   // out tile [bh][s], pad 72
    int t = blockIdx.x >> 1, sh = blockIdx.x & 1;
    int tid = threadIdx.x, l = tid&63, w = tid>>6;
    int l31 = l&31, hi = l>>5;
    int g = w & 1, sg = w >> 1;      // wave's bh-group / s-subgroup
    v8h aa[4];
    const _Float16* qbt = qb + ((size_t)t<<12);
    #pragma unroll
    for (int k0=0;k0<4;++k0)
        aa[k0] = *(const v8h*)(qbt + (g*32 + l31)*64 + k0*16 + hi*8);

    const float* pkt = posk + ((size_t)t<<16);
    int sbase = sh*512;
    int lrow = (l>>4), lcol = (l&15)*4;      // within-wave load geometry

    v4f pf[4];
    #pragma unroll
    for (int j=0;j<4;++j)
        pf[j] = *(const v4f*)(pkt + (size_t)(sbase + w*16 + j*4 + lrow)*64 + lcol);

    int obh = tid>>2;
    int osl = (tid&3)*16;
    int ob  = obh>>3;
    const int* mbase = mask + (((size_t)(ob*Tt + t))<<10);
    _Float16* sbb = Sb + (((size_t)(t*64 + obh))<<10);

    // write chunk0 to Pl[0]
    #pragma unroll
    for (int j=0;j<4;++j){
        v4h hv; hv[0]=(_Float16)pf[j][0]; hv[1]=(_Float16)pf[j][1];
                hv[2]=(_Float16)pf[j][2]; hv[3]=(_Float16)pf[j][3];
        *(v4h*)&Pl[0][swz(w*16 + j*4 + lrow, lcol)] = hv;
    }
    __syncthreads();

    for (int sc=0; sc<8; ++sc){
        int cur = sc&1;
        int s0 = sbase + sc*64;
        if (sc < 7){
            #pragma unroll
            for (int j=0;j<4;++j)
                pf[j] = *(const v4f*)(pkt + (size_t)(s0 + 64 + w*16 + j*4 + lrow)*64 + lcol);
        }
        int4 mq[4];
        #pragma unroll
        for (int j=0;j<4;++j)
            mq[j] = *(const int4*)(mbase + s0 + osl + j*4);
        v8h bfr[4];
        #pragma unroll
        for (int k0=0;k0<4;++k0)
            bfr[k0] = *(v8h*)&Pl[cur][swz(sg*32 + l31, k0*16 + hi*8)];
        v16f acc = {};
        #pragma unroll
        for (int k0=0;k0<4;++k0) acc = MFMA3216(aa[k0], bfr[k0], acc);
        #pragma unroll
        for (int r=0;r<16;++r){
            int bh = g*32 + (r&3) + 4*hi + 8*(r>>2);
            Ol[cur][bh*72 + sg*32 + l31] = (_Float16)acc[r];
        }
        if (sc < 7){
            #pragma unroll
            for (int j=0;j<4;++j){
                v4h hv; hv[0]=(_Float16)pf[j][0]; hv[1]=(_Float16)pf[j][1];
                        hv[2]=(_Float16)pf[j][2]; hv[3]=(_Float16)pf[j][3];
                *(v4h*)&Pl[cur^1][swz(w*16 + j*4 + lrow, lcol)] = hv;
            }
        }
        __syncthreads();
        v8h o0 = *(v8h*)&Ol[cur][obh*72 + osl];
        v8h o1 = *(v8h*)&Ol[cur][obh*72 + osl + 8];
        const _Float16 NEG = (_Float16)(-30000.f);
        int mm[16] = {mq[0].x,mq[0].y,mq[0].z,mq[0].w, mq[1].x,mq[1].y,mq[1].z,mq[1].w,
                      mq[2].x,mq[2].y,mq[2].z,mq[2].w, mq[3].x,mq[3].y,mq[3].z,mq[3].w};
        #pragma unroll
        for (int j=0;j<8;++j){ if(!mm[j]) o0[j]=NEG; if(!mm[8+j]) o1[j]=NEG; }
        *(v8h*)(sbb + s0 + osl)     = o0;
        *(v8h*)(sbb + s0 + osl + 8) = o1;
    }
}

// ---------------- flash v4: swapped QK + double-buffered LDS, 1 barrier/chunk
// grid (64 bh, 8 t-tiles of 128), 512 thr. Schedule per chunk:
//   issue loads(sc+1) -> compute from buf[cur] -> write buf[cur^1] -> barrier
__global__ __launch_bounds__(512) void k_flash(const _Float16* __restrict__ qs,
                                               const _Float16* __restrict__ kbuf,
                                               const _Float16* __restrict__ vbuf,
                                               const _Float16* __restrict__ Sb,
                                               _Float16* __restrict__ ao){
    __shared__ _Float16 Kl[2][64*64];    // [s][d] swizzled
    __shared__ _Float16 Vt[2][64*64];    // [d][s] swizzled
    __shared__ _Float16 Bl[2][128*64];   // bias chunk then P (wave-private rows)
    int bh = blockIdx.x; int b = bh>>3, h = bh&7;
    int t0 = blockIdx.y*128;
    int tid = threadIdx.x, l = tid&63, w = tid>>6, l15 = l&15, lq = l>>4;

    v8h qa[2];
    #pragma unroll
    for (int u=0;u<2;++u)
        qa[u] = *(const v8h*)(qs + ((size_t)(b*Tt + t0 + w*16 + l15))*NFf + h*DKk + u*32 + lq*8);

    v4f O[4] = {};
    float m_l = -1e30f, l_l = 0.f;

    int kr = tid>>3, kseg = (tid&7)*8;
    int vs = tid&63, vd0 = (tid>>6)*8;
    int br = tid>>2, bhf = (tid&3)*16;
    const _Float16* kbase = kbuf + ((size_t)(b*Tt + kr))*NFf + h*DKk + kseg;
    const _Float16* vbase = vbuf + ((size_t)(b*Tt + vs))*NFf + h*DKk + vd0;
    const _Float16* bbase = Sb + (((size_t)((t0+br)*64 + bh))<<10) + bhf;

    // prefetch + stage chunk 0 into buffer 0
    v8h pk = *(const v8h*)kbase;
    v8h pv = *(const v8h*)vbase;
    v8h pb0 = *(const v8h*)bbase;
    v8h pb1 = *((const v8h*)bbase + 1);
    st8(&Kl[0][swz(kr, kseg)], pk);
    #pragma unroll
    for (int j=0;j<8;j++) Vt[0][swz(vd0+j, vs)] = pv[j];
    st8(&Bl[0][swz(br, bhf)],   pb0);
    st8(&Bl[0][swz(br, bhf+8)], pb1);
    __syncthreads();

    for (int sc=0; sc<16; ++sc){
        int cur = sc&1;
        // issue next chunk's global loads (land during compute)
        if (sc < 15){
            size_t soff = (size_t)(sc+1)*64;
            pk  = *(const v8h*)(kbase + soff*NFf);
            pv  = *(const v8h*)(vbase + soff*NFf);
            pb0 = *(const v8h*)(bbase + soff);
            pb1 = *((const v8h*)(bbase + soff) + 1);
        }

        // QK^T swapped from buf[cur]: col = t (l15), row = s
        v4f sv[4];
        #pragma unroll
        for (int nt=0; nt<4; ++nt){
            v8h kb0 = *(v8h*)&Kl[cur][swz(nt*16+l15, lq*8)];
            v8h kb1 = *(v8h*)&Kl[cur][swz(nt*16+l15, 32+lq*8)];
            v4f a = {};
            a = MFMA32(kb0, qa[0], a);
            a = MFMA32(kb1, qa[1], a);
            v4h bl4 = *(v4h*)&Bl[cur][swz(w*16 + l15, nt*16 + lq*4)];
            #pragma unroll
            for (int i=0;i<4;i++) a[i] += (float)bl4[i];
            sv[nt] = a;
        }
        float mx = fmaxf(fmaxf(fmaxf(sv[0][0],sv[0][1]),fmaxf(sv[0][2],sv[0][3])),
                   fmaxf(fmaxf(fmaxf(sv[1][0],sv[1][1]),fmaxf(sv[1][2],sv[1][3])),
                   fmaxf(fmaxf(fmaxf(sv[2][0],sv[2][1]),fmaxf(sv[2][2],sv[2][3])),
                         fmaxf(fmaxf(sv[3][0],sv[3][1]),fmaxf(sv[3][2],sv[3][3])))));
        mx = fmaxf(mx, __shfl_xor(mx,16));
        mx = fmaxf(mx, __shfl_xor(mx,32));
        float mn = fmaxf(m_l, mx);
        if (__any(mn - m_l > 0.f)){
            float rsc = exp2f(m_l - mn);
            m_l = mn; l_l *= rsc;
            float rscB[4];
            #pragma unroll
            for (int i=0;i<4;i++) rscB[i] = __shfl(rsc, lq*4+i);
            #pragma unroll
            for (int nt=0; nt<4; ++nt)
                #pragma unroll
                for (int i=0;i<4;i++) O[nt][i] *= rscB[i];
        }
        float ps = 0.f;
        #pragma unroll
        for (int nt=0; nt<4; ++nt){
            v4h ph;
            #pragma unroll
            for (int i=0;i<4;i++){
                float p = exp2f(sv[nt][i] - m_l);
                ph[i] = (_Float16)p;
                ps += p;
            }
            *(v4h*)&Bl[cur][swz(w*16 + l15, nt*16 + lq*4)] = ph;   // wave-private rows
        }
        ps += __shfl_xor(ps,16);
        ps += __shfl_xor(ps,32);
        l_l += ps;
        // PV from buf[cur]
        {
            v8h pa0 = *(v8h*)&Bl[cur][swz(w*16+l15, lq*8)];
            v8h pa1 = *(v8h*)&Bl[cur][swz(w*16+l15, 32+lq*8)];
            #pragma unroll
            for (int nt=0; nt<4; ++nt){
                v8h vb0 = *(v8h*)&Vt[cur][swz(nt*16+l15, lq*8)];
                v8h vb1 = *(v8h*)&Vt[cur][swz(nt*16+l15, 32+lq*8)];
                O[nt] = MFMA32(pa0, vb0, O[nt]);
                O[nt] = MFMA32(pa1, vb1, O[nt]);
            }
        }
        // write staged chunk sc+1 into buf[cur^1]; prior reads of buf[cur^1]
        // finished before the barrier ending iteration sc-1
        if (sc < 15){
            st8(&Kl[cur^1][swz(kr, kseg)], pk);
            #pragma unroll
            for (int j=0;j<8;j++) Vt[cur^1][swz(vd0+j, vs)] = pv[j];
            st8(&Bl[cur^1][swz(br, bhf)],   pb0);
            st8(&Bl[cur^1][swz(br, bhf+8)], pb1);
        }
        __syncthreads();
    }

    float rl = (l_l > 0.f) ? 1.f/l_l : 0.f;
    float rlB[4];
    #pragma unroll
    for (int i=0;i<4;i++) rlB[i] = __shfl(rl, lq*4+i);
    #pragma unroll
    for (int i=0;i<4;i++){
        int row = t0 + w*16 + lq*4 + i;
        #pragma unroll
        for (int nt=0; nt<4; ++nt)
            ao[((size_t)(b*Tt + row))*NFf + h*DKk + nt*16 + l15] = (_Float16)(O[nt][i]*rlB[i]);
    }
}

// ---------------- launch ----------------
extern "C" void kernel_launch(void* const* d_in, const int* in_sizes, int n_in,
                              void* d_out, int out_size, void* d_ws, size_t ws_size,
                              hipStream_t stream) {
    const float* x       = (const float*)d_in[0];
    const float* cond    = (const float*)d_in[1];
    const float* pos_k   = (const float*)d_in[2];
    const int*   mask    = (const int*)  d_in[3];
    const float* ln_g    = (const float*)d_in[4];
    const float* ln_b    = (const float*)d_in[5];
    const float* Wq      = (const float*)d_in[6];
    const float* bq      = (const float*)d_in[7];
    const float* Wk      = (const float*)d_in[8];
    const float* bk      = (const float*)d_in[9];
    const float* Wv      = (const float*)d_in[10];
    const float* bv      = (const float*)d_in[11];
    const float* Wo      = (const float*)d_in[12];
    const float* bo      = (const float*)d_in[13];
    const float* Wc      = (const float*)d_in[14];
    const float* bc      = (const float*)d_in[15];
    float* out = (float*)d_out;

    char* base = (char*)d_ws;
    const size_t OFF_S    = 0;                       // 134217728 B fp16 Sb
    const size_t OFF_XN   = 134217728;
    const size_t OFF_Q    = OFF_XN  + 8388608;
    const size_t OFF_QB   = OFF_Q   + 8388608;
    const size_t OFF_K    = OFF_QB  + 8388608;
    const size_t OFF_V    = OFF_K   + 8388608;
    const size_t OFF_AO   = OFF_V   + 8388608;
    const size_t OFF_WKT  = OFF_AO  + 8388608;       // 524288
    const size_t OFF_WVT  = OFF_WKT + 524288;
    const size_t OFF_WOT  = OFF_WVT + 524288;
    const size_t OFF_WQT  = OFF_WOT + 524288;        // 524288
    const size_t OFF_WCH  = OFF_WQT + 524288;        // 262144
    const size_t OFF_WCQT = OFF_WCH + 262144;        // 262144
    const size_t OFF_BCQ  = OFF_WCQT + 262144;       // 2048
    const size_t OFF_ZERO = OFF_BCQ + 2048;          // 1024

    _Float16* xn    = (_Float16*)(base + OFF_XN);
    _Float16* qbuf  = (_Float16*)(base + OFF_Q);
    _Float16* qb    = (_Float16*)(base + OFF_QB);
    _Float16* kb    = (_Float16*)(base + OFF_K);
    _Float16* vb    = (_Float16*)(base + OFF_V);
    _Float16* ao    = (_Float16*)(base + OFF_AO);
    _Float16* Sb    = (_Float16*)(base + OFF_S);
    _Float16* WkT   = (_Float16*)(base + OFF_WKT);
    _Float16* WvT   = (_Float16*)(base + OFF_WVT);
    _Float16* WoT   = (_Float16*)(base + OFF_WOT);
    _Float16* WqT   = (_Float16*)(base + OFF_WQT);
    _Float16* WcH   = (_Float16*)(base + OFF_WCH);
    _Float16* wcqT  = (_Float16*)(base + OFF_WCQT);
    float*    bcq   = (float*)(base + OFF_BCQ);
    float*    zero  = (float*)(base + OFF_ZERO);

    k_ln<<<dim3(Bb*Tt), dim3(256), 0, stream>>>(x, ln_g, ln_b, xn);
    k_prep<<<dim3(8,8,5), dim3(256), 0, stream>>>(Wk, Wv, Wo, Wq, WkT, WvT, WoT, WqT, Wc, WcH, bq, bcq, zero);
    k_bcqp<<<dim3(16), dim3(512), 0, stream>>>(bc, Wq, bcq);

    // wcqT(512x256) = WqT(512x512) @ WcH(256x512)^T  via GEMM v3
    k_gemm<_Float16,_Float16,false><<<dim3(2,4), dim3(512), 0, stream>>>(WqT, WcH, zero, wcqT, 512, 256, 512, 1.f, nullptr);

    // q projection: writes scaled qbuf AND scaled transposed qb
    k_gemm<float,_Float16,true><<<dim3(4,64), dim3(512), 0, stream>>>(cond, wcqT, bcq, qbuf, Bb*Tt, 512, 256, SCQ, qb);
    // fused K+V projection
    k_gemmkv<<<dim3(4,64), dim3(512), 0, stream>>>(xn, WkT, WvT, bk, bv, kb, vb);

    k_bias<<<dim3(2048), dim3(256), 0, stream>>>(qb, pos_k, mask, Sb);
    k_flash<<<dim3(64,8), dim3(512), 0, stream>>>(qbuf, kb, vb, Sb, ao);

    k_gemm<_Float16,float,false><<<dim3(4,64), dim3(512), 0, stream>>>(ao, WoT, bo, out, Bb*Tt, 512, 512, 1.f, nullptr);
}